// Round 1
// 616.726 us; speedup vs baseline: 1.1558x; 1.1558x over previous
//
#include <hip/hip_runtime.h>

typedef unsigned short ushort_t;
typedef __bf16 bf16x8 __attribute__((ext_vector_type(8)));
typedef float floatx4 __attribute__((ext_vector_type(4)));

__device__ __forceinline__ ushort_t f2bf(float f) {
  union { float f; unsigned int u; } c; c.f = f;
  unsigned int r = c.u + 0x7FFFu + ((c.u >> 16) & 1u);
  return (ushort_t)(r >> 16);
}

// Async 16B global->LDS (lane-contiguous LDS dest required: base + lane*16).
__device__ __forceinline__ void async16(const ushort_t* g, ushort_t* l) {
  __builtin_amdgcn_global_load_lds(
      (const __attribute__((address_space(1))) unsigned int*)g,
      (__attribute__((address_space(3))) unsigned int*)l, 16, 0, 0);
}

// ============================================================================
// 256x256 8-phase GEMM (m201 template: T2 LDS swizzle + T3/T4 counted vmcnt +
// T5 setprio). C[M,N] = A[M,K] x Bt[N,K], bf16 in, fp32 accum.
// 512 threads = 8 waves (2M x 4N); per-wave 128x64 out; BK=64, 2 K-tiles/iter.
// LDS 128 KiB: As/Bs[2][256][64]. Swizzle: 16B-block ^= (row&7), both sides.
// BIASM: 0 none, 1 bias[m], 2 bias[n].  POOLM: 0 none, 1 pool n-pairs,
// 2 pool m-pairs.  OUTF32: write float.
// ============================================================================
template<int BIASM, int POOLM, bool OUTF32>
__global__ __launch_bounds__(512, 2)
void gemm256(const ushort_t* __restrict__ A, long aStr,
             const ushort_t* __restrict__ B, long bStr,
             void* __restrict__ Cp, long cStr,
             int K, int lda, int ldb, int ldc,
             const float* __restrict__ bias, float scale)
{
  __shared__ ushort_t As[2][256][64];
  __shared__ ushort_t Bs[2][256][64];

  A += (long)blockIdx.z * aStr;
  B += (long)blockIdx.z * bStr;
  float* Cf = (float*)Cp + (OUTF32 ? (long)blockIdx.z * cStr : 0);
  ushort_t* Cb = (ushort_t*)Cp + (OUTF32 ? 0 : (long)blockIdx.z * cStr);
  const int m0 = blockIdx.y * 256;
  const int n0 = blockIdx.x * 256;
  const int tid = threadIdx.x;
  const int lane = tid & 63;
  const int wid = tid >> 6;
  const int wm = wid >> 2;        // 0..1
  const int wn = wid & 3;         // 0..3
  const int l15 = lane & 15;
  const int lq  = lane >> 4;      // 0..3

  // Staging: thread t covers 16B block (srow, t&7) of a 64-row pass.
  // LDS dest is LINEAR (gload_lds constraint); source col is pre-swizzled so
  // physical block pb holds logical block pb ^ (row&7)  (involution).
  const int srow = tid >> 3;                         // 0..63
  const int scb  = (((tid & 7) ^ (srow & 7)) << 3);  // swizzled src col (bf16)
  const int dcb  = (tid & 7) << 3;                   // linear LDS dest col

  const ushort_t* gA = A + (long)(m0 + srow) * lda + scb;
  const ushort_t* gB = B + (long)(n0 + srow) * ldb + scb;

  // Read-side swizzled col offsets (bf16 units) for kk=0 / kk=1.
  // logical block = kk*4 + lq ; row&7 == l15&7 for all fragment rows.
  const int pb0 = ((lq ^ (l15 & 7)) << 3);
  const int pb1 = (((4 | lq) ^ (l15 & 7)) << 3);

  floatx4 acc[8][4];
#pragma unroll
  for (int i = 0; i < 8; ++i)
#pragma unroll
    for (int j = 0; j < 4; ++j)
#pragma unroll
      for (int r = 0; r < 4; ++r) acc[i][j][r] = 0.0f;

  bf16x8 aA[4][2], bB0[2][2], bB1[2][2];

  const int NT = K >> 6;   // K-tiles of 64
  const int NI = NT >> 1;  // iterations (2 tiles each)

#define STAGE_A(sl, hf, kt) do { \
    const ushort_t* _s = gA + (long)((hf) * 128) * lda + ((kt) << 6); \
    async16(_s,                  &As[sl][(hf)*128      + srow][dcb]); \
    async16(_s + (long)64 * lda, &As[sl][(hf)*128 + 64 + srow][dcb]); \
  } while (0)
#define STAGE_B(sl, hf, kt) do { \
    const ushort_t* _s = gB + (long)((hf) * 128) * ldb + ((kt) << 6); \
    async16(_s,                  &Bs[sl][(hf)*128      + srow][dcb]); \
    async16(_s + (long)64 * ldb, &Bs[sl][(hf)*128 + 64 + srow][dcb]); \
  } while (0)
#define LD_A(sl, mh) do { \
    _Pragma("unroll") for (int _i = 0; _i < 4; ++_i) { \
      const int _r = wm*128 + (mh)*64 + _i*16 + l15; \
      aA[_i][0] = *(const bf16x8*)&As[sl][_r][pb0]; \
      aA[_i][1] = *(const bf16x8*)&As[sl][_r][pb1]; } \
  } while (0)
#define LD_B(sl, nh, dst) do { \
    _Pragma("unroll") for (int _j = 0; _j < 2; ++_j) { \
      const int _r = wn*64 + (nh)*32 + _j*16 + l15; \
      dst[_j][0] = *(const bf16x8*)&Bs[sl][_r][pb0]; \
      dst[_j][1] = *(const bf16x8*)&Bs[sl][_r][pb1]; } \
  } while (0)
#define MMA(mh, nh, bfr) do { \
    __builtin_amdgcn_s_setprio(1); \
    _Pragma("unroll") for (int _i = 0; _i < 4; ++_i) \
    _Pragma("unroll") for (int _j = 0; _j < 2; ++_j) { \
      floatx4& _c = acc[(mh)*4 + _i][(nh)*2 + _j]; \
      _c = __builtin_amdgcn_mfma_f32_16x16x32_bf16(aA[_i][0], (bfr)[_j][0], _c, 0, 0, 0); \
      _c = __builtin_amdgcn_mfma_f32_16x16x32_bf16(aA[_i][1], (bfr)[_j][1], _c, 0, 0, 0); } \
    __builtin_amdgcn_s_setprio(0); \
  } while (0)
#define SBAR  __builtin_amdgcn_s_barrier()
#define LGKM0 asm volatile("s_waitcnt lgkmcnt(0)" ::: "memory")
#define VM4   asm volatile("s_waitcnt vmcnt(4)" ::: "memory")
#define VM0   asm volatile("s_waitcnt vmcnt(0)" ::: "memory")

  // Prologue: tile0 (4 halves) + A0(1), B1(1). vmcnt(4) leaves newest 2 halves
  // (4 loads) in flight; tile0 fully landed for phase 1.
  STAGE_A(0, 0, 0); STAGE_A(0, 1, 0); STAGE_B(0, 0, 0); STAGE_B(0, 1, 0);
  STAGE_A(1, 0, 1); STAGE_B(1, 1, 1);
  VM4; SBAR;

  // Quadrant order per tile: (0,0),(0,1),(1,1),(1,0) -> A read once/half,
  // both B halves stay live. Stage schedule (1 half/phase) derived from
  // per-region last-read times; waits only at phases 4 and 8 (counted).
  for (int i = 0; i < NI - 1; ++i) {
    const int t1 = 2*i + 1, t2 = 2*i + 2, t3 = 2*i + 3;
    // ph1: compute tile 2i quad(0,0); stage A1(2i+1)
    LD_A(0, 0); LD_B(0, 0, bB0); STAGE_A(1, 1, t1);
    SBAR; LGKM0; MMA(0, 0, bB0); SBAR;
    // ph2: quad(0,1); stage B0(2i+1)
    LD_B(0, 1, bB1); STAGE_B(1, 0, t1);
    SBAR; LGKM0; MMA(0, 1, bB1); SBAR;
    // ph3: quad(1,1); stage A0(2i+2)
    LD_A(0, 1); STAGE_A(0, 0, t2);
    SBAR; LGKM0; MMA(1, 1, bB1); SBAR;
    // ph4: quad(1,0); stage B1(2i+2); wait -> tile 2i+1 resident
    STAGE_B(0, 1, t2);
    SBAR; LGKM0; MMA(1, 0, bB0); VM4; SBAR;
    // ph5: tile 2i+1 quad(0,0); stage A1(2i+2)
    LD_A(1, 0); LD_B(1, 0, bB0); STAGE_A(0, 1, t2);
    SBAR; LGKM0; MMA(0, 0, bB0); SBAR;
    // ph6: quad(0,1); stage B0(2i+2)
    LD_B(1, 1, bB1); STAGE_B(0, 0, t2);
    SBAR; LGKM0; MMA(0, 1, bB1); SBAR;
    // ph7: quad(1,1); stage A0(2i+3)
    LD_A(1, 1); STAGE_A(1, 0, t3);
    SBAR; LGKM0; MMA(1, 1, bB1); SBAR;
    // ph8: quad(1,0); stage B1(2i+3); wait -> tile 2i+2 resident
    STAGE_B(1, 1, t3);
    SBAR; LGKM0; MMA(1, 0, bB0); VM4; SBAR;
  }
  // Peeled final iteration (tiles NT-2, NT-1): only the two mandatory stages,
  // full drain at ph4.
  {
    const int t1 = NT - 1;
    LD_A(0, 0); LD_B(0, 0, bB0); STAGE_A(1, 1, t1);
    SBAR; LGKM0; MMA(0, 0, bB0); SBAR;
    LD_B(0, 1, bB1); STAGE_B(1, 0, t1);
    SBAR; LGKM0; MMA(0, 1, bB1); SBAR;
    LD_A(0, 1);
    SBAR; LGKM0; MMA(1, 1, bB1); SBAR;
    SBAR; LGKM0; MMA(1, 0, bB0); VM0; SBAR;
    LD_A(1, 0); LD_B(1, 0, bB0);
    SBAR; LGKM0; MMA(0, 0, bB0); SBAR;
    LD_B(1, 1, bB1);
    SBAR; LGKM0; MMA(0, 1, bB1); SBAR;
    LD_A(1, 1);
    SBAR; LGKM0; MMA(1, 1, bB1); SBAR;
    LGKM0; MMA(1, 0, bB0);
  }
#undef STAGE_A
#undef STAGE_B
#undef LD_A
#undef LD_B
#undef MMA
#undef SBAR
#undef LGKM0
#undef VM4
#undef VM0

  // Epilogue. acc[mi][nj]: m-off = (mi>>2)*64 + (mi&3)*16 ; n-off = (nj>>1)*32
  // + (nj&1)*16 (quadrant decomposition).
#pragma unroll
  for (int mi = 0; mi < 8; ++mi) {
    const int mbase = m0 + wm*128 + (mi >> 2)*64 + (mi & 3)*16 + lq*4;
#pragma unroll
    for (int nj = 0; nj < 4; ++nj) {
      const int n = n0 + wn*64 + (nj >> 1)*32 + (nj & 1)*16 + l15;
      float v[4];
#pragma unroll
      for (int r = 0; r < 4; ++r) {
        v[r] = acc[mi][nj][r] * scale;
        if (BIASM == 1) v[r] += bias[mbase + r];
      }
      if (BIASM == 2) {
        const float bn_ = bias[n];
#pragma unroll
        for (int r = 0; r < 4; ++r) v[r] += bn_;
      }
      if (POOLM == 0) {
#pragma unroll
        for (int r = 0; r < 4; ++r) {
          if (OUTF32) Cf[(long)(mbase + r) * ldc + n] = v[r];
          else        Cb[(long)(mbase + r) * ldc + n] = f2bf(v[r]);
        }
      } else if (POOLM == 1) {
#pragma unroll
        for (int r = 0; r < 4; ++r) {
          float o = __shfl_xor(v[r], 1);
          float w = fmaxf(v[r], o);
          if ((lane & 1) == 0) {
            if (OUTF32) Cf[(long)(mbase + r) * ldc + (n >> 1)] = w;
            else        Cb[(long)(mbase + r) * ldc + (n >> 1)] = f2bf(w);
          }
        }
      } else {  // POOLM == 2
        float w0 = fmaxf(v[0], v[1]);
        float w1 = fmaxf(v[2], v[3]);
        const int mh = mbase >> 1;
        if (OUTF32) {
          Cf[(long)mh * ldc + n] = w0;
          Cf[(long)(mh + 1) * ldc + n] = w1;
        } else {
          Cb[(long)mh * ldc + n] = f2bf(w0);
          Cb[(long)(mh + 1) * ldc + n] = f2bf(w1);
        }
      }
    }
  }
}

// dst[t][c] = bf16(src[c][t]) per batch (blockIdx.z). src: (Rr, Cl) fp32.
__global__ __launch_bounds__(256)
void transpose_f32_bf16(const float* __restrict__ src, ushort_t* __restrict__ dst,
                        int Rr, int Cl)
{
  __shared__ ushort_t tile[32][33];
  const long boff = (long)blockIdx.z * Rr * Cl;
  const int tx = threadIdx.x & 31;
  const int ty = threadIdx.x >> 5;
  const int c0 = blockIdx.x * 32;
  const int r0 = blockIdx.y * 32;
#pragma unroll
  for (int i = 0; i < 4; ++i) {
    int r = ty + i * 8;
    tile[r][tx] = f2bf(src[boff + (long)(r0 + r) * Cl + c0 + tx]);
  }
  __syncthreads();
#pragma unroll
  for (int i = 0; i < 4; ++i) {
    int r = ty + i * 8;
    dst[boff + (long)(c0 + r) * Rr + r0 + tx] = tile[tx][r];
  }
}

// Convert 4 equal-size fp32 weight buffers to contiguous bf16 regions.
__global__ __launch_bounds__(256)
void convert4(const float* __restrict__ a, const float* __restrict__ b,
              const float* __restrict__ c, const float* __restrict__ d,
              ushort_t* __restrict__ dst, int n)
{
  const float* srcs[4] = {a, b, c, d};
  const float* s = srcs[blockIdx.y];
  int i = blockIdx.x * 256 + threadIdx.x;
  if (i < n) dst[(long)blockIdx.y * n + i] = f2bf(s[i]);
}

// One block per channel c: mean/rstd over (B,T) of y (B,C,T) fp32.
__global__ __launch_bounds__(256)
void bn_stats(const float* __restrict__ y, float* __restrict__ stats)
{
  const int c = blockIdx.x;
  float s = 0.0f, s2 = 0.0f;
  for (int b = 0; b < 16; ++b) {
    const float* row = y + ((long)b * 1024 + c) * 2048;
    for (int t = threadIdx.x; t < 2048; t += 256) {
      float v = row[t];
      s += v; s2 += v * v;
    }
  }
#pragma unroll
  for (int o = 32; o > 0; o >>= 1) { s += __shfl_down(s, o); s2 += __shfl_down(s2, o); }
  __shared__ float red[8];
  const int lane = threadIdx.x & 63, w = threadIdx.x >> 6;
  if (lane == 0) { red[w] = s; red[4 + w] = s2; }
  __syncthreads();
  if (threadIdx.x == 0) {
    s = red[0] + red[1] + red[2] + red[3];
    s2 = red[4] + red[5] + red[6] + red[7];
    const float inv = 1.0f / (16.0f * 2048.0f);
    float mean = s * inv;
    float var = s2 * inv - mean * mean;
    stats[c * 2] = mean;
    stats[c * 2 + 1] = rsqrtf(var + 1e-5f);
  }
}

// In-place: y = gamma*(y-mean)*rstd + beta + x ; one block per (b,c) row.
__global__ __launch_bounds__(256)
void bn_apply(float* __restrict__ y, const float* __restrict__ x,
              const float* __restrict__ stats, const float* __restrict__ gamma,
              const float* __restrict__ beta)
{
  const int bc = blockIdx.x;
  const int c = bc & 1023;
  const long off = (long)bc * 2048;
  const float mean = stats[c * 2], rstd = stats[c * 2 + 1];
  const float g = gamma[c] * rstd;
  const float bt = beta[c];
  for (int t = threadIdx.x; t < 2048; t += 256) {
    y[off + t] = (y[off + t] - mean) * g + bt + x[off + t];
  }
}

extern "C" void kernel_launch(void* const* d_in, const int* in_sizes, int n_in,
                              void* d_out, int out_size, void* d_ws, size_t ws_size,
                              hipStream_t stream) {
  (void)in_sizes; (void)n_in; (void)out_size; (void)ws_size;
  const float* x  = (const float*)d_in[0];
  const float* Wq = (const float*)d_in[1];
  const float* bq = (const float*)d_in[2];
  const float* Wk = (const float*)d_in[3];
  const float* bk = (const float*)d_in[4];
  const float* Wv = (const float*)d_in[5];
  const float* bv = (const float*)d_in[6];
  const float* Wo = (const float*)d_in[7];
  const float* bo = (const float*)d_in[8];
  const float* gamma = (const float*)d_in[9];
  const float* beta  = (const float*)d_in[10];
  float* out = (float*)d_out;

  const int Cc = 1024, T = 2048, D = 512, S = 1024;

  // ws: flat layout, no aliasing. ~239 MB used of 512 MiB.
  ushort_t* ws   = (ushort_t*)d_ws;
  ushort_t* xT   = ws;                 // (B,T,C) 33,554,432
  ushort_t* Qt   = ws + 33554432;      // (B,T,D) 16,777,216
  ushort_t* Kt   = ws + 50331648;      // (B,S,D)  8,388,608
  ushort_t* V    = ws + 58720256;      // (B,D,S)  8,388,608
  ushort_t* attn = ws + 67108864;      // (B,T,S) 33,554,432
  ushort_t* out2 = ws + 100663296;     // (B,T,D) 16,777,216
  ushort_t* Wq_b = ws + 117440512;     //    524,288
  ushort_t* Wk_b = ws + 117964800;
  ushort_t* Wv_b = ws + 118489088;
  ushort_t* Wo_b = ws + 119013376;
  float*    stats = (float*)(ws + 119537664);  // 2048 floats

  dim3 blk(256);
  dim3 blk512(512);

  // 0. Weights fp32 -> bf16.
  convert4<<<dim3(2048, 4), blk, 0, stream>>>(Wq, Wk, Wv, Wo, Wq_b, D * Cc);

  // 1. xT = bf16(x^T) for all 16 batches.
  transpose_f32_bf16<<<dim3(T / 32, Cc / 32, 16), blk, 0, stream>>>(x, xT, Cc, T);

  // 2. Qt (T,D): M=T, N=D, K=C; bias bq by n.
  gemm256<2, 0, false><<<dim3(D / 256, T / 256, 16), blk512, 0, stream>>>(
      xT, (long)T * Cc, Wq_b, 0, Qt, (long)T * D, Cc, Cc, Cc, D, bq, 1.0f);
  // 3. Kt (S,D): same GEMM, maxpool over time pairs (m), bias bk by n.
  gemm256<2, 2, false><<<dim3(D / 256, T / 256, 16), blk512, 0, stream>>>(
      xT, (long)T * Cc, Wk_b, 0, Kt, (long)S * D, Cc, Cc, Cc, D, bk, 1.0f);
  // 4. V (D,S): M=D, N=T, K=C; maxpool over time pairs (n), bias bv by m.
  gemm256<1, 1, false><<<dim3(T / 256, D / 256, 16), blk512, 0, stream>>>(
      Wv_b, 0, xT, (long)T * Cc, V, (long)D * S, Cc, Cc, Cc, S, bv, 1.0f);

  // 5. attn = (Qt x Kt^T)/T : M=T, N=S, K=D.
  gemm256<0, 0, false><<<dim3(S / 256, T / 256, 16), blk512, 0, stream>>>(
      Qt, (long)T * D, Kt, (long)S * D, attn, (long)T * S,
      D, D, D, S, nullptr, 1.0f / 2048.0f);
  // 6. out2 = attn x V^T : M=T, N=D, K=S.
  gemm256<0, 0, false><<<dim3(D / 256, T / 256, 16), blk512, 0, stream>>>(
      attn, (long)T * S, V, (long)D * S, out2, (long)T * D,
      S, S, S, D, nullptr, 1.0f);

  // 7. y = Wo x out2^T + bo -> d_out (fp32, (B,C,T)).
  gemm256<1, 0, true><<<dim3(T / 256, Cc / 256, 16), blk512, 0, stream>>>(
      Wo_b, 0, out2, (long)T * D, out, (long)Cc * T, D, D, D, T, bo, 1.0f);

  // 8. BatchNorm (training stats, biased var) + residual, in place on d_out.
  bn_stats<<<dim3(1024), blk, 0, stream>>>(out, stats);
  bn_apply<<<dim3(16384), blk, 0, stream>>>(out, x, stats, gamma, beta);
}

// Round 2
// 554.001 us; speedup vs baseline: 1.2866x; 1.1132x over previous
//
#include <hip/hip_runtime.h>

typedef unsigned short ushort_t;
typedef __bf16 bf16x8 __attribute__((ext_vector_type(8)));
typedef float floatx4 __attribute__((ext_vector_type(4)));
typedef ushort_t ushortx8 __attribute__((ext_vector_type(8)));

__device__ __forceinline__ ushort_t f2bf(float f) {
  union { float f; unsigned int u; } c; c.f = f;
  unsigned int r = c.u + 0x7FFFu + ((c.u >> 16) & 1u);
  return (ushort_t)(r >> 16);
}

// Async 16B global->LDS (lane-contiguous LDS dest required: base + lane*16).
__device__ __forceinline__ void async16(const ushort_t* g, ushort_t* l) {
  __builtin_amdgcn_global_load_lds(
      (const __attribute__((address_space(1))) unsigned int*)g,
      (__attribute__((address_space(3))) unsigned int*)l, 16, 0, 0);
}

// ============================================================================
// 256x256 8-phase GEMM (m201 template: T2 LDS swizzle + T3/T4 counted vmcnt +
// T5 setprio). C[M,N] = A[M,K] x Bt[N,K], bf16 in, fp32 accum.
// 512 threads = 8 waves (2M x 4N); per-wave 128x64 out; BK=64, 2 K-tiles/iter.
// LDS 128 KiB: As/Bs[2][256][64]. Swizzle: 16B-block ^= (row&7), both sides.
// BIASM: 0 none, 1 bias[m], 2 bias[n].  POOLM: 0 none, 1 pool n-pairs,
// 2 pool m-pairs.  OUTF32: write float.
// ============================================================================
template<int BIASM, int POOLM, bool OUTF32>
__global__ __launch_bounds__(512, 2)
void gemm256(const ushort_t* __restrict__ A, long aStr,
             const ushort_t* __restrict__ B, long bStr,
             void* __restrict__ Cp, long cStr,
             int K, int lda, int ldb, int ldc,
             const float* __restrict__ bias, float scale)
{
  __shared__ ushort_t As[2][256][64];
  __shared__ ushort_t Bs[2][256][64];

  A += (long)blockIdx.z * aStr;
  B += (long)blockIdx.z * bStr;
  float* Cf = (float*)Cp + (OUTF32 ? (long)blockIdx.z * cStr : 0);
  ushort_t* Cb = (ushort_t*)Cp + (OUTF32 ? 0 : (long)blockIdx.z * cStr);
  const int m0 = blockIdx.y * 256;
  const int n0 = blockIdx.x * 256;
  const int tid = threadIdx.x;
  const int lane = tid & 63;
  const int wid = tid >> 6;
  const int wm = wid >> 2;        // 0..1
  const int wn = wid & 3;         // 0..3
  const int l15 = lane & 15;
  const int lq  = lane >> 4;      // 0..3

  // Staging: thread t covers 16B block (srow, t&7) of a 64-row pass.
  // LDS dest is LINEAR (gload_lds constraint); source col is pre-swizzled so
  // physical block pb holds logical block pb ^ (row&7)  (involution).
  const int srow = tid >> 3;                         // 0..63
  const int scb  = (((tid & 7) ^ (srow & 7)) << 3);  // swizzled src col (bf16)
  const int dcb  = (tid & 7) << 3;                   // linear LDS dest col

  const ushort_t* gA = A + (long)(m0 + srow) * lda + scb;
  const ushort_t* gB = B + (long)(n0 + srow) * ldb + scb;

  // Read-side swizzled col offsets (bf16 units) for kk=0 / kk=1.
  // logical block = kk*4 + lq ; row&7 == l15&7 for all fragment rows.
  const int pb0 = ((lq ^ (l15 & 7)) << 3);
  const int pb1 = (((4 | lq) ^ (l15 & 7)) << 3);

  floatx4 acc[8][4];
#pragma unroll
  for (int i = 0; i < 8; ++i)
#pragma unroll
    for (int j = 0; j < 4; ++j)
#pragma unroll
      for (int r = 0; r < 4; ++r) acc[i][j][r] = 0.0f;

  bf16x8 aA[4][2], bB0[2][2], bB1[2][2];

  const int NT = K >> 6;   // K-tiles of 64
  const int NI = NT >> 1;  // iterations (2 tiles each)

#define STAGE_A(sl, hf, kt) do { \
    const ushort_t* _s = gA + (long)((hf) * 128) * lda + ((kt) << 6); \
    async16(_s,                  &As[sl][(hf)*128      + srow][dcb]); \
    async16(_s + (long)64 * lda, &As[sl][(hf)*128 + 64 + srow][dcb]); \
  } while (0)
#define STAGE_B(sl, hf, kt) do { \
    const ushort_t* _s = gB + (long)((hf) * 128) * ldb + ((kt) << 6); \
    async16(_s,                  &Bs[sl][(hf)*128      + srow][dcb]); \
    async16(_s + (long)64 * ldb, &Bs[sl][(hf)*128 + 64 + srow][dcb]); \
  } while (0)
#define LD_A(sl, mh) do { \
    _Pragma("unroll") for (int _i = 0; _i < 4; ++_i) { \
      const int _r = wm*128 + (mh)*64 + _i*16 + l15; \
      aA[_i][0] = *(const bf16x8*)&As[sl][_r][pb0]; \
      aA[_i][1] = *(const bf16x8*)&As[sl][_r][pb1]; } \
  } while (0)
#define LD_B(sl, nh, dst) do { \
    _Pragma("unroll") for (int _j = 0; _j < 2; ++_j) { \
      const int _r = wn*64 + (nh)*32 + _j*16 + l15; \
      dst[_j][0] = *(const bf16x8*)&Bs[sl][_r][pb0]; \
      dst[_j][1] = *(const bf16x8*)&Bs[sl][_r][pb1]; } \
  } while (0)
#define MMA(mh, nh, bfr) do { \
    __builtin_amdgcn_s_setprio(1); \
    _Pragma("unroll") for (int _i = 0; _i < 4; ++_i) \
    _Pragma("unroll") for (int _j = 0; _j < 2; ++_j) { \
      floatx4& _c = acc[(mh)*4 + _i][(nh)*2 + _j]; \
      _c = __builtin_amdgcn_mfma_f32_16x16x32_bf16(aA[_i][0], (bfr)[_j][0], _c, 0, 0, 0); \
      _c = __builtin_amdgcn_mfma_f32_16x16x32_bf16(aA[_i][1], (bfr)[_j][1], _c, 0, 0, 0); } \
    __builtin_amdgcn_s_setprio(0); \
  } while (0)
#define SBAR  __builtin_amdgcn_s_barrier()
#define LGKM0 asm volatile("s_waitcnt lgkmcnt(0)" ::: "memory")
#define VM4   asm volatile("s_waitcnt vmcnt(4)" ::: "memory")
#define VM0   asm volatile("s_waitcnt vmcnt(0)" ::: "memory")

  // Prologue: tile0 (4 halves) + A0(1), B1(1). vmcnt(4) leaves newest 2 halves
  // (4 loads) in flight; tile0 fully landed for phase 1.
  STAGE_A(0, 0, 0); STAGE_A(0, 1, 0); STAGE_B(0, 0, 0); STAGE_B(0, 1, 0);
  STAGE_A(1, 0, 1); STAGE_B(1, 1, 1);
  VM4; SBAR;

  // Quadrant order per tile: (0,0),(0,1),(1,1),(1,0) -> A read once/half,
  // both B halves stay live. Stage schedule (1 half/phase) derived from
  // per-region last-read times; waits only at phases 4 and 8 (counted).
  for (int i = 0; i < NI - 1; ++i) {
    const int t1 = 2*i + 1, t2 = 2*i + 2, t3 = 2*i + 3;
    // ph1: compute tile 2i quad(0,0); stage A1(2i+1)
    LD_A(0, 0); LD_B(0, 0, bB0); STAGE_A(1, 1, t1);
    SBAR; LGKM0; MMA(0, 0, bB0); SBAR;
    // ph2: quad(0,1); stage B0(2i+1)
    LD_B(0, 1, bB1); STAGE_B(1, 0, t1);
    SBAR; LGKM0; MMA(0, 1, bB1); SBAR;
    // ph3: quad(1,1); stage A0(2i+2)
    LD_A(0, 1); STAGE_A(0, 0, t2);
    SBAR; LGKM0; MMA(1, 1, bB1); SBAR;
    // ph4: quad(1,0); stage B1(2i+2); wait -> tile 2i+1 resident
    STAGE_B(0, 1, t2);
    SBAR; LGKM0; MMA(1, 0, bB0); VM4; SBAR;
    // ph5: tile 2i+1 quad(0,0); stage A1(2i+2)
    LD_A(1, 0); LD_B(1, 0, bB0); STAGE_A(0, 1, t2);
    SBAR; LGKM0; MMA(0, 0, bB0); SBAR;
    // ph6: quad(0,1); stage B0(2i+2)
    LD_B(1, 1, bB1); STAGE_B(0, 0, t2);
    SBAR; LGKM0; MMA(0, 1, bB1); SBAR;
    // ph7: quad(1,1); stage A0(2i+3)
    LD_A(1, 1); STAGE_A(1, 0, t3);
    SBAR; LGKM0; MMA(1, 1, bB1); SBAR;
    // ph8: quad(1,0); stage B1(2i+3); wait -> tile 2i+2 resident
    STAGE_B(1, 1, t3);
    SBAR; LGKM0; MMA(1, 0, bB0); VM4; SBAR;
  }
  // Peeled final iteration (tiles NT-2, NT-1): only the two mandatory stages,
  // full drain at ph4.
  {
    const int t1 = NT - 1;
    LD_A(0, 0); LD_B(0, 0, bB0); STAGE_A(1, 1, t1);
    SBAR; LGKM0; MMA(0, 0, bB0); SBAR;
    LD_B(0, 1, bB1); STAGE_B(1, 0, t1);
    SBAR; LGKM0; MMA(0, 1, bB1); SBAR;
    LD_A(0, 1);
    SBAR; LGKM0; MMA(1, 1, bB1); SBAR;
    SBAR; LGKM0; MMA(1, 0, bB0); VM0; SBAR;
    LD_A(1, 0); LD_B(1, 0, bB0);
    SBAR; LGKM0; MMA(0, 0, bB0); SBAR;
    LD_B(1, 1, bB1);
    SBAR; LGKM0; MMA(0, 1, bB1); SBAR;
    LD_A(1, 1);
    SBAR; LGKM0; MMA(1, 1, bB1); SBAR;
    LGKM0; MMA(1, 0, bB0);
  }
#undef STAGE_A
#undef STAGE_B
#undef LD_A
#undef LD_B
#undef MMA
#undef SBAR
#undef LGKM0
#undef VM4
#undef VM0

  // Epilogue. acc[mi][nj]: m-off = (mi>>2)*64 + (mi&3)*16 ; n-off = (nj>>1)*32
  // + (nj&1)*16 (quadrant decomposition).
#pragma unroll
  for (int mi = 0; mi < 8; ++mi) {
    const int mbase = m0 + wm*128 + (mi >> 2)*64 + (mi & 3)*16 + lq*4;
#pragma unroll
    for (int nj = 0; nj < 4; ++nj) {
      const int n = n0 + wn*64 + (nj >> 1)*32 + (nj & 1)*16 + l15;
      float v[4];
#pragma unroll
      for (int r = 0; r < 4; ++r) {
        v[r] = acc[mi][nj][r] * scale;
        if (BIASM == 1) v[r] += bias[mbase + r];
      }
      if (BIASM == 2) {
        const float bn_ = bias[n];
#pragma unroll
        for (int r = 0; r < 4; ++r) v[r] += bn_;
      }
      if (POOLM == 0) {
#pragma unroll
        for (int r = 0; r < 4; ++r) {
          if (OUTF32) Cf[(long)(mbase + r) * ldc + n] = v[r];
          else        Cb[(long)(mbase + r) * ldc + n] = f2bf(v[r]);
        }
      } else if (POOLM == 1) {
#pragma unroll
        for (int r = 0; r < 4; ++r) {
          float o = __shfl_xor(v[r], 1);
          float w = fmaxf(v[r], o);
          if ((lane & 1) == 0) {
            if (OUTF32) Cf[(long)(mbase + r) * ldc + (n >> 1)] = w;
            else        Cb[(long)(mbase + r) * ldc + (n >> 1)] = f2bf(w);
          }
        }
      } else {  // POOLM == 2
        float w0 = fmaxf(v[0], v[1]);
        float w1 = fmaxf(v[2], v[3]);
        const int mh = mbase >> 1;
        if (OUTF32) {
          Cf[(long)mh * ldc + n] = w0;
          Cf[(long)(mh + 1) * ldc + n] = w1;
        } else {
          Cb[(long)mh * ldc + n] = f2bf(w0);
          Cb[(long)(mh + 1) * ldc + n] = f2bf(w1);
        }
      }
    }
  }
}

// dst[t][c] = bf16(src[c][t]) per batch z. src (Rr=C rows, Cl=T cols) fp32.
// 64x64 tiles; float4 global reads, ushort8 global writes.
// LDS tileT[64][72]: 144B row stride (odd multiple of 16B -> aligned vector
// reads with even bank spread); writes are 2B scalar (HBM-bound kernel,
// LDS conflicts are not on the critical path).
__global__ __launch_bounds__(256)
void transpose_f32_bf16(const float* __restrict__ src, ushort_t* __restrict__ dst,
                        int Rr, int Cl)
{
  __shared__ ushort_t tileT[64][72];
  const long boff = (long)blockIdx.z * Rr * Cl;
  const int t0 = blockIdx.x * 64;   // col tile (contiguous dim of src)
  const int r0 = blockIdx.y * 64;   // row tile (contiguous dim of dst)
  const int tx = threadIdx.x & 15;
  const int ty = threadIdx.x >> 4;
#pragma unroll
  for (int i = 0; i < 4; ++i) {
    const int c = ty + 16 * i;      // tile row index (src row r0+c)
    floatx4 v = *(const floatx4*)&src[boff + (long)(r0 + c) * Cl + t0 + 4 * tx];
#pragma unroll
    for (int j = 0; j < 4; ++j) tileT[4 * tx + j][c] = f2bf(v[j]);
  }
  __syncthreads();
  const int cx = threadIdx.x & 7;
  const int tw = threadIdx.x >> 3;
#pragma unroll
  for (int i = 0; i < 2; ++i) {
    const int t = tw + 32 * i;
    ushortx8 w = *(const ushortx8*)&tileT[t][8 * cx];
    *(ushortx8*)&dst[boff + (long)(t0 + t) * Rr + r0 + 8 * cx] = w;
  }
}

// Convert 4 equal-size fp32 weight buffers to contiguous bf16 regions.
__global__ __launch_bounds__(256)
void convert4(const float* __restrict__ a, const float* __restrict__ b,
              const float* __restrict__ c, const float* __restrict__ d,
              ushort_t* __restrict__ dst, int n)
{
  const float* srcs[4] = {a, b, c, d};
  const float* s = srcs[blockIdx.y];
  int i = blockIdx.x * 256 + threadIdx.x;
  if (i < n) dst[(long)blockIdx.y * n + i] = f2bf(s[i]);
}

// One block per channel c: mean/rstd over (B,T) of y (B,C,T) fp32. float4.
__global__ __launch_bounds__(256)
void bn_stats(const float* __restrict__ y, float* __restrict__ stats)
{
  const int c = blockIdx.x;
  float s = 0.0f, s2 = 0.0f;
  for (int b = 0; b < 16; ++b) {
    const floatx4* row = (const floatx4*)(y + ((long)b * 1024 + c) * 2048);
    for (int t = threadIdx.x; t < 512; t += 256) {
      floatx4 v = row[t];
#pragma unroll
      for (int r = 0; r < 4; ++r) { s += v[r]; s2 += v[r] * v[r]; }
    }
  }
#pragma unroll
  for (int o = 32; o > 0; o >>= 1) { s += __shfl_down(s, o); s2 += __shfl_down(s2, o); }
  __shared__ float red[8];
  const int lane = threadIdx.x & 63, w = threadIdx.x >> 6;
  if (lane == 0) { red[w] = s; red[4 + w] = s2; }
  __syncthreads();
  if (threadIdx.x == 0) {
    s = red[0] + red[1] + red[2] + red[3];
    s2 = red[4] + red[5] + red[6] + red[7];
    const float inv = 1.0f / (16.0f * 2048.0f);
    float mean = s * inv;
    float var = s2 * inv - mean * mean;
    stats[c * 2] = mean;
    stats[c * 2 + 1] = rsqrtf(var + 1e-5f);
  }
}

// In-place: y = gamma*(y-mean)*rstd + beta + x ; one block per (b,c) row. float4.
__global__ __launch_bounds__(256)
void bn_apply(float* __restrict__ y, const float* __restrict__ x,
              const float* __restrict__ stats, const float* __restrict__ gamma,
              const float* __restrict__ beta)
{
  const int bc = blockIdx.x;
  const int c = bc & 1023;
  const long off = (long)bc * 2048;
  const float mean = stats[c * 2], rstd = stats[c * 2 + 1];
  const float g = gamma[c] * rstd;
  const float bt = beta[c];
  floatx4* yp = (floatx4*)(y + off);
  const floatx4* xp = (const floatx4*)(x + off);
  for (int t = threadIdx.x; t < 512; t += 256) {
    floatx4 v = yp[t];
    floatx4 xv = xp[t];
#pragma unroll
    for (int r = 0; r < 4; ++r) v[r] = (v[r] - mean) * g + bt + xv[r];
    yp[t] = v;
  }
}

extern "C" void kernel_launch(void* const* d_in, const int* in_sizes, int n_in,
                              void* d_out, int out_size, void* d_ws, size_t ws_size,
                              hipStream_t stream) {
  (void)in_sizes; (void)n_in; (void)out_size; (void)ws_size;
  const float* x  = (const float*)d_in[0];
  const float* Wq = (const float*)d_in[1];
  const float* bq = (const float*)d_in[2];
  const float* Wk = (const float*)d_in[3];
  const float* bk = (const float*)d_in[4];
  const float* Wv = (const float*)d_in[5];
  const float* bv = (const float*)d_in[6];
  const float* Wo = (const float*)d_in[7];
  const float* bo = (const float*)d_in[8];
  const float* gamma = (const float*)d_in[9];
  const float* beta  = (const float*)d_in[10];
  float* out = (float*)d_out;

  const int Cc = 1024, T = 2048, D = 512, S = 1024;

  // Softmax-free attention reassociates: out2 = Q (K^T V^T)/T.
  // Wt[i][j] = sum_s V[i][s]*Kd[j][s]  (DxD per batch) replaces the TxS attn.
  // ws: flat layout, no aliasing. ~180 MB used.
  ushort_t* ws   = (ushort_t*)d_ws;
  ushort_t* xT   = ws;                 // (B,T,C) 33,554,432
  ushort_t* Qt   = ws + 33554432;      // (B,T,D) 16,777,216
  ushort_t* Kd   = ws + 50331648;      // (B,D,S)  8,388,608
  ushort_t* V    = ws + 58720256;      // (B,D,S)  8,388,608
  ushort_t* Wt   = ws + 67108864;      // (B,D,D)  4,194,304
  ushort_t* out2 = ws + 71303168;      // (B,T,D) 16,777,216
  ushort_t* Wq_b = ws + 88080384;      //    524,288
  ushort_t* Wk_b = ws + 88604672;
  ushort_t* Wv_b = ws + 89128960;
  ushort_t* Wo_b = ws + 89653248;
  float*    stats = (float*)(ws + 90177536);  // 2048 floats

  dim3 blk(256);
  dim3 blk512(512);

  // 0. Weights fp32 -> bf16.
  convert4<<<dim3(2048, 4), blk, 0, stream>>>(Wq, Wk, Wv, Wo, Wq_b, D * Cc);

  // 1. xT = bf16(x^T) for all 16 batches (64x64 vectorized tiles).
  transpose_f32_bf16<<<dim3(T / 64, Cc / 64, 16), blk, 0, stream>>>(x, xT, Cc, T);

  // 2. Qt (T,D): M=T, N=D, K=C; bias bq by n.
  gemm256<2, 0, false><<<dim3(D / 256, T / 256, 16), blk512, 0, stream>>>(
      xT, (long)T * Cc, Wq_b, 0, Qt, (long)T * D, Cc, Cc, Cc, D, bq, 1.0f);
  // 3. Kd (D,S): M=D, N=T, K=C; maxpool over time pairs (n), bias bk by m.
  gemm256<1, 1, false><<<dim3(T / 256, D / 256, 16), blk512, 0, stream>>>(
      Wk_b, 0, xT, (long)T * Cc, Kd, (long)D * S, Cc, Cc, Cc, S, bk, 1.0f);
  // 4. V (D,S): M=D, N=T, K=C; maxpool over time pairs (n), bias bv by m.
  gemm256<1, 1, false><<<dim3(T / 256, D / 256, 16), blk512, 0, stream>>>(
      Wv_b, 0, xT, (long)T * Cc, V, (long)D * S, Cc, Cc, Cc, S, bv, 1.0f);

  // 5. Wt (D,D) = V x Kd^T : M=D, N=D, K=S.
  gemm256<0, 0, false><<<dim3(D / 256, D / 256, 16), blk512, 0, stream>>>(
      V, (long)D * S, Kd, (long)D * S, Wt, (long)D * D,
      S, S, S, D, nullptr, 1.0f);
  // 6. out2 (T,D) = Qt x Wt^T / T : M=T, N=D, K=D.
  gemm256<0, 0, false><<<dim3(D / 256, T / 256, 16), blk512, 0, stream>>>(
      Qt, (long)T * D, Wt, (long)D * D, out2, (long)T * D,
      D, D, D, D, nullptr, 1.0f / 2048.0f);

  // 7. y = Wo x out2^T + bo -> d_out (fp32, (B,C,T)).
  gemm256<1, 0, true><<<dim3(T / 256, Cc / 256, 16), blk512, 0, stream>>>(
      Wo_b, 0, out2, (long)T * D, out, (long)Cc * T, D, D, D, T, bo, 1.0f);

  // 8. BatchNorm (training stats, biased var) + residual, in place on d_out.
  bn_stats<<<dim3(1024), blk, 0, stream>>>(out, stats);
  bn_apply<<<dim3(16384), blk, 0, stream>>>(out, x, stats, gamma, beta);
}

// Round 3
// 535.210 us; speedup vs baseline: 1.3318x; 1.0351x over previous
//
#include <hip/hip_runtime.h>

typedef unsigned short ushort_t;
typedef __bf16 bf16x8 __attribute__((ext_vector_type(8)));
typedef float floatx4 __attribute__((ext_vector_type(4)));
typedef ushort_t ushortx8 __attribute__((ext_vector_type(8)));

__device__ __forceinline__ ushort_t f2bf(float f) {
  union { float f; unsigned int u; } c; c.f = f;
  unsigned int r = c.u + 0x7FFFu + ((c.u >> 16) & 1u);
  return (ushort_t)(r >> 16);
}

// Async 16B global->LDS (lane-contiguous LDS dest required: base + lane*16).
__device__ __forceinline__ void async16(const ushort_t* g, ushort_t* l) {
  __builtin_amdgcn_global_load_lds(
      (const __attribute__((address_space(1))) unsigned int*)g,
      (__attribute__((address_space(3))) unsigned int*)l, 16, 0, 0);
}

// ============================================================================
// 256x256 8-phase GEMM (m201 template: T2 LDS swizzle + T3/T4 counted vmcnt +
// T5 setprio). C[M,N] = A[M,K] x Bt[N,K], bf16 in, fp32 accum.
// 512 threads = 8 waves (2M x 4N); per-wave 128x64 out; BK=64, 2 K-tiles/iter.
// LDS 128 KiB: As/Bs[2][256][64]. Swizzle: 16B-block ^= (row&7), both sides.
// BIASM: 0 none, 1 bias[m], 2 bias[n].  POOLM: 0 none, 1 pool n-pairs,
// 2 pool m-pairs.  OUTF32: write float.  STATS: per-channel(m) sum/sumsq
// partials -> pstat[(z*gridDim.x+bx)*1024 + m] (float2), for fused BN stats.
// ============================================================================
template<int BIASM, int POOLM, bool OUTF32, bool STATS = false>
__global__ __launch_bounds__(512, 2)
void gemm256(const ushort_t* __restrict__ A, long aStr,
             const ushort_t* __restrict__ B, long bStr,
             void* __restrict__ Cp, long cStr,
             int K, int lda, int ldb, int ldc,
             const float* __restrict__ bias, float scale,
             float2* __restrict__ pstat = nullptr)
{
  __shared__ ushort_t As[2][256][64];
  __shared__ ushort_t Bs[2][256][64];
  __shared__ float2 part[4][256];   // STATS only: per-wn-wave channel partials

  A += (long)blockIdx.z * aStr;
  B += (long)blockIdx.z * bStr;
  float* Cf = (float*)Cp + (OUTF32 ? (long)blockIdx.z * cStr : 0);
  ushort_t* Cb = (ushort_t*)Cp + (OUTF32 ? 0 : (long)blockIdx.z * cStr);
  const int m0 = blockIdx.y * 256;
  const int n0 = blockIdx.x * 256;
  const int tid = threadIdx.x;
  const int lane = tid & 63;
  const int wid = tid >> 6;
  const int wm = wid >> 2;        // 0..1
  const int wn = wid & 3;         // 0..3
  const int l15 = lane & 15;
  const int lq  = lane >> 4;      // 0..3

  // Staging: thread t covers 16B block (srow, t&7) of a 64-row pass.
  // LDS dest is LINEAR (gload_lds constraint); source col is pre-swizzled so
  // physical block pb holds logical block pb ^ (row&7)  (involution).
  const int srow = tid >> 3;                         // 0..63
  const int scb  = (((tid & 7) ^ (srow & 7)) << 3);  // swizzled src col (bf16)
  const int dcb  = (tid & 7) << 3;                   // linear LDS dest col

  const ushort_t* gA = A + (long)(m0 + srow) * lda + scb;
  const ushort_t* gB = B + (long)(n0 + srow) * ldb + scb;

  // Read-side swizzled col offsets (bf16 units) for kk=0 / kk=1.
  // logical block = kk*4 + lq ; row&7 == l15&7 for all fragment rows.
  const int pb0 = ((lq ^ (l15 & 7)) << 3);
  const int pb1 = (((4 | lq) ^ (l15 & 7)) << 3);

  floatx4 acc[8][4];
#pragma unroll
  for (int i = 0; i < 8; ++i)
#pragma unroll
    for (int j = 0; j < 4; ++j)
#pragma unroll
      for (int r = 0; r < 4; ++r) acc[i][j][r] = 0.0f;

  bf16x8 aA[4][2], bB0[2][2], bB1[2][2];

  const int NT = K >> 6;   // K-tiles of 64
  const int NI = NT >> 1;  // iterations (2 tiles each)

#define STAGE_A(sl, hf, kt) do { \
    const ushort_t* _s = gA + (long)((hf) * 128) * lda + ((kt) << 6); \
    async16(_s,                  &As[sl][(hf)*128      + srow][dcb]); \
    async16(_s + (long)64 * lda, &As[sl][(hf)*128 + 64 + srow][dcb]); \
  } while (0)
#define STAGE_B(sl, hf, kt) do { \
    const ushort_t* _s = gB + (long)((hf) * 128) * ldb + ((kt) << 6); \
    async16(_s,                  &Bs[sl][(hf)*128      + srow][dcb]); \
    async16(_s + (long)64 * ldb, &Bs[sl][(hf)*128 + 64 + srow][dcb]); \
  } while (0)
#define LD_A(sl, mh) do { \
    _Pragma("unroll") for (int _i = 0; _i < 4; ++_i) { \
      const int _r = wm*128 + (mh)*64 + _i*16 + l15; \
      aA[_i][0] = *(const bf16x8*)&As[sl][_r][pb0]; \
      aA[_i][1] = *(const bf16x8*)&As[sl][_r][pb1]; } \
  } while (0)
#define LD_B(sl, nh, dst) do { \
    _Pragma("unroll") for (int _j = 0; _j < 2; ++_j) { \
      const int _r = wn*64 + (nh)*32 + _j*16 + l15; \
      dst[_j][0] = *(const bf16x8*)&Bs[sl][_r][pb0]; \
      dst[_j][1] = *(const bf16x8*)&Bs[sl][_r][pb1]; } \
  } while (0)
#define MMA(mh, nh, bfr) do { \
    __builtin_amdgcn_s_setprio(1); \
    _Pragma("unroll") for (int _i = 0; _i < 4; ++_i) \
    _Pragma("unroll") for (int _j = 0; _j < 2; ++_j) { \
      floatx4& _c = acc[(mh)*4 + _i][(nh)*2 + _j]; \
      _c = __builtin_amdgcn_mfma_f32_16x16x32_bf16(aA[_i][0], (bfr)[_j][0], _c, 0, 0, 0); \
      _c = __builtin_amdgcn_mfma_f32_16x16x32_bf16(aA[_i][1], (bfr)[_j][1], _c, 0, 0, 0); } \
    __builtin_amdgcn_s_setprio(0); \
  } while (0)
#define SBAR  __builtin_amdgcn_s_barrier()
#define LGKM0 asm volatile("s_waitcnt lgkmcnt(0)" ::: "memory")
#define VM4   asm volatile("s_waitcnt vmcnt(4)" ::: "memory")
#define VM0   asm volatile("s_waitcnt vmcnt(0)" ::: "memory")

  // Prologue: tile0 (4 halves) + A0(1), B1(1). vmcnt(4) leaves newest 2 halves
  // (4 loads) in flight; tile0 fully landed for phase 1.
  STAGE_A(0, 0, 0); STAGE_A(0, 1, 0); STAGE_B(0, 0, 0); STAGE_B(0, 1, 0);
  STAGE_A(1, 0, 1); STAGE_B(1, 1, 1);
  VM4; SBAR;

  // Quadrant order per tile: (0,0),(0,1),(1,1),(1,0) -> A read once/half,
  // both B halves stay live. Stage schedule (1 half/phase) derived from
  // per-region last-read times; waits only at phases 4 and 8 (counted).
  for (int i = 0; i < NI - 1; ++i) {
    const int t1 = 2*i + 1, t2 = 2*i + 2, t3 = 2*i + 3;
    // ph1: compute tile 2i quad(0,0); stage A1(2i+1)
    LD_A(0, 0); LD_B(0, 0, bB0); STAGE_A(1, 1, t1);
    SBAR; LGKM0; MMA(0, 0, bB0); SBAR;
    // ph2: quad(0,1); stage B0(2i+1)
    LD_B(0, 1, bB1); STAGE_B(1, 0, t1);
    SBAR; LGKM0; MMA(0, 1, bB1); SBAR;
    // ph3: quad(1,1); stage A0(2i+2)
    LD_A(0, 1); STAGE_A(0, 0, t2);
    SBAR; LGKM0; MMA(1, 1, bB1); SBAR;
    // ph4: quad(1,0); stage B1(2i+2); wait -> tile 2i+1 resident
    STAGE_B(0, 1, t2);
    SBAR; LGKM0; MMA(1, 0, bB0); VM4; SBAR;
    // ph5: tile 2i+1 quad(0,0); stage A1(2i+2)
    LD_A(1, 0); LD_B(1, 0, bB0); STAGE_A(0, 1, t2);
    SBAR; LGKM0; MMA(0, 0, bB0); SBAR;
    // ph6: quad(0,1); stage B0(2i+2)
    LD_B(1, 1, bB1); STAGE_B(0, 0, t2);
    SBAR; LGKM0; MMA(0, 1, bB1); SBAR;
    // ph7: quad(1,1); stage A0(2i+3)
    LD_A(1, 1); STAGE_A(1, 0, t3);
    SBAR; LGKM0; MMA(1, 1, bB1); SBAR;
    // ph8: quad(1,0); stage B1(2i+3); wait -> tile 2i+2 resident
    STAGE_B(1, 1, t3);
    SBAR; LGKM0; MMA(1, 0, bB0); VM4; SBAR;
  }
  // Peeled final iteration (tiles NT-2, NT-1): only the two mandatory stages,
  // full drain at ph4.
  {
    const int t1 = NT - 1;
    LD_A(0, 0); LD_B(0, 0, bB0); STAGE_A(1, 1, t1);
    SBAR; LGKM0; MMA(0, 0, bB0); SBAR;
    LD_B(0, 1, bB1); STAGE_B(1, 0, t1);
    SBAR; LGKM0; MMA(0, 1, bB1); SBAR;
    LD_A(0, 1);
    SBAR; LGKM0; MMA(1, 1, bB1); SBAR;
    SBAR; LGKM0; MMA(1, 0, bB0); VM0; SBAR;
    LD_A(1, 0); LD_B(1, 0, bB0);
    SBAR; LGKM0; MMA(0, 0, bB0); SBAR;
    LD_B(1, 1, bB1);
    SBAR; LGKM0; MMA(0, 1, bB1); SBAR;
    LD_A(1, 1);
    SBAR; LGKM0; MMA(1, 1, bB1); SBAR;
    LGKM0; MMA(1, 0, bB0);
  }
#undef STAGE_A
#undef STAGE_B
#undef LD_A
#undef LD_B
#undef MMA
#undef SBAR
#undef LGKM0
#undef VM4
#undef VM0

  // Epilogue. acc[mi][nj]: m-off = (mi>>2)*64 + (mi&3)*16 ; n-off = (nj>>1)*32
  // + (nj&1)*16 (quadrant decomposition).
#pragma unroll
  for (int mi = 0; mi < 8; ++mi) {
    const int mbase = m0 + wm*128 + (mi >> 2)*64 + (mi & 3)*16 + lq*4;
    float ss[4], ss2[4];
    if (STATS) {
#pragma unroll
      for (int r = 0; r < 4; ++r) { ss[r] = 0.0f; ss2[r] = 0.0f; }
    }
#pragma unroll
    for (int nj = 0; nj < 4; ++nj) {
      const int n = n0 + wn*64 + (nj >> 1)*32 + (nj & 1)*16 + l15;
      float v[4];
#pragma unroll
      for (int r = 0; r < 4; ++r) {
        v[r] = acc[mi][nj][r] * scale;
        if (BIASM == 1) v[r] += bias[mbase + r];
      }
      if (BIASM == 2) {
        const float bn_ = bias[n];
#pragma unroll
        for (int r = 0; r < 4; ++r) v[r] += bn_;
      }
      if (STATS) {
#pragma unroll
        for (int r = 0; r < 4; ++r) { ss[r] += v[r]; ss2[r] += v[r] * v[r]; }
      }
      if (POOLM == 0) {
#pragma unroll
        for (int r = 0; r < 4; ++r) {
          if (OUTF32) Cf[(long)(mbase + r) * ldc + n] = v[r];
          else        Cb[(long)(mbase + r) * ldc + n] = f2bf(v[r]);
        }
      } else if (POOLM == 1) {
#pragma unroll
        for (int r = 0; r < 4; ++r) {
          float o = __shfl_xor(v[r], 1);
          float w = fmaxf(v[r], o);
          if ((lane & 1) == 0) {
            if (OUTF32) Cf[(long)(mbase + r) * ldc + (n >> 1)] = w;
            else        Cb[(long)(mbase + r) * ldc + (n >> 1)] = f2bf(w);
          }
        }
      } else {  // POOLM == 2
        float w0 = fmaxf(v[0], v[1]);
        float w1 = fmaxf(v[2], v[3]);
        const int mh = mbase >> 1;
        if (OUTF32) {
          Cf[(long)mh * ldc + n] = w0;
          Cf[(long)(mh + 1) * ldc + n] = w1;
        } else {
          Cb[(long)mh * ldc + n] = f2bf(w0);
          Cb[(long)(mh + 1) * ldc + n] = f2bf(w1);
        }
      }
    }
    if (STATS) {
      // Reduce over the 16 l15 lanes (same lq => same channels, different n).
#pragma unroll
      for (int o = 1; o < 16; o <<= 1) {
#pragma unroll
        for (int r = 0; r < 4; ++r) {
          ss[r]  += __shfl_xor(ss[r],  o);
          ss2[r] += __shfl_xor(ss2[r], o);
        }
      }
      if (l15 == 0) {
        const int chb = wm*128 + (mi >> 2)*64 + (mi & 3)*16 + lq*4;
#pragma unroll
        for (int r = 0; r < 4; ++r) part[wn][chb + r] = make_float2(ss[r], ss2[r]);
      }
    }
  }
  if (STATS) {
    __syncthreads();
    if (tid < 256) {
      float2 p0 = part[0][tid], p1 = part[1][tid], p2 = part[2][tid], p3 = part[3][tid];
      float2 p = make_float2(p0.x + p1.x + p2.x + p3.x, p0.y + p1.y + p2.y + p3.y);
      pstat[((long)blockIdx.z * gridDim.x + blockIdx.x) * 1024 + m0 + tid] = p;
    }
  }
}

// dst[t][c] = bf16(src[c][t]) per batch z. src (Rr=C rows, Cl=T cols) fp32.
// 64x64 tiles; float4 global reads, ushort8 global writes.
__global__ __launch_bounds__(256)
void transpose_f32_bf16(const float* __restrict__ src, ushort_t* __restrict__ dst,
                        int Rr, int Cl)
{
  __shared__ ushort_t tileT[64][72];
  const long boff = (long)blockIdx.z * Rr * Cl;
  const int t0 = blockIdx.x * 64;   // col tile (contiguous dim of src)
  const int r0 = blockIdx.y * 64;   // row tile (contiguous dim of dst)
  const int tx = threadIdx.x & 15;
  const int ty = threadIdx.x >> 4;
#pragma unroll
  for (int i = 0; i < 4; ++i) {
    const int c = ty + 16 * i;      // tile row index (src row r0+c)
    floatx4 v = *(const floatx4*)&src[boff + (long)(r0 + c) * Cl + t0 + 4 * tx];
#pragma unroll
    for (int j = 0; j < 4; ++j) tileT[4 * tx + j][c] = f2bf(v[j]);
  }
  __syncthreads();
  const int cx = threadIdx.x & 7;
  const int tw = threadIdx.x >> 3;
#pragma unroll
  for (int i = 0; i < 2; ++i) {
    const int t = tw + 32 * i;
    ushortx8 w = *(const ushortx8*)&tileT[t][8 * cx];
    *(ushortx8*)&dst[boff + (long)(t0 + t) * Rr + r0 + 8 * cx] = w;
  }
}

// Convert 4 equal-size fp32 weight buffers to contiguous bf16 regions, and
// build concatenated bias bkv[1024] = {bk, bv}.
__global__ __launch_bounds__(256)
void convert4(const float* __restrict__ a, const float* __restrict__ b,
              const float* __restrict__ c, const float* __restrict__ d,
              ushort_t* __restrict__ dst, int n,
              const float* __restrict__ bk, const float* __restrict__ bv,
              float* __restrict__ bkv)
{
  const float* srcs[4] = {a, b, c, d};
  const float* s = srcs[blockIdx.y];
  int i = blockIdx.x * 256 + threadIdx.x;
  if (i < n) dst[(long)blockIdx.y * n + i] = f2bf(s[i]);
  if (blockIdx.y == 0 && blockIdx.x == 0) {
    for (int j = threadIdx.x; j < 1024; j += 256)
      bkv[j] = (j < 512) ? bk[j] : bv[j - 512];
  }
}

// stats[c] from 128 per-block partials: mean/rstd. grid(1024), 64 threads.
__global__ __launch_bounds__(64)
void bn_finalize(const float2* __restrict__ pstat, float* __restrict__ stats)
{
  const int c = blockIdx.x;
  const int lane = threadIdx.x;
  float2 a = pstat[(long)lane * 1024 + c];
  float2 b = pstat[(long)(lane + 64) * 1024 + c];
  float s = a.x + b.x, s2 = a.y + b.y;
#pragma unroll
  for (int o = 32; o > 0; o >>= 1) { s += __shfl_down(s, o); s2 += __shfl_down(s2, o); }
  if (lane == 0) {
    const float inv = 1.0f / (16.0f * 2048.0f);
    float mean = s * inv;
    float var = s2 * inv - mean * mean;
    stats[c * 2] = mean;
    stats[c * 2 + 1] = rsqrtf(var + 1e-5f);
  }
}

// In-place: y = gamma*(y-mean)*rstd + beta + x ; one block per (b,c) row. float4.
__global__ __launch_bounds__(256)
void bn_apply(float* __restrict__ y, const float* __restrict__ x,
              const float* __restrict__ stats, const float* __restrict__ gamma,
              const float* __restrict__ beta)
{
  const int bc = blockIdx.x;
  const int c = bc & 1023;
  const long off = (long)bc * 2048;
  const float mean = stats[c * 2], rstd = stats[c * 2 + 1];
  const float g = gamma[c] * rstd;
  const float bt = beta[c];
  floatx4* yp = (floatx4*)(y + off);
  const floatx4* xp = (const floatx4*)(x + off);
  for (int t = threadIdx.x; t < 512; t += 256) {
    floatx4 v = yp[t];
    floatx4 xv = xp[t];
#pragma unroll
    for (int r = 0; r < 4; ++r) v[r] = (v[r] - mean) * g + bt + xv[r];
    yp[t] = v;
  }
}

extern "C" void kernel_launch(void* const* d_in, const int* in_sizes, int n_in,
                              void* d_out, int out_size, void* d_ws, size_t ws_size,
                              hipStream_t stream) {
  (void)in_sizes; (void)n_in; (void)out_size; (void)ws_size;
  const float* x  = (const float*)d_in[0];
  const float* Wq = (const float*)d_in[1];
  const float* bq = (const float*)d_in[2];
  const float* Wk = (const float*)d_in[3];
  const float* bk = (const float*)d_in[4];
  const float* Wv = (const float*)d_in[5];
  const float* bv = (const float*)d_in[6];
  const float* Wo = (const float*)d_in[7];
  const float* bo = (const float*)d_in[8];
  const float* gamma = (const float*)d_in[9];
  const float* beta  = (const float*)d_in[10];
  float* out = (float*)d_out;

  const int Cc = 1024, T = 2048, D = 512, S = 1024;

  // Full algebraic chain (softmax-free attention):
  //   y = Wo (V Kd^T) Qt^T / T + bo  with K/V maxpooled.
  //   WtT = Kd V^T ; Wco = Wo WtT^T / T ; y = Wco Qt^T + bo.
  // BN stats fused into the y-GEMM epilogue (partials -> bn_finalize).
  ushort_t* ws   = (ushort_t*)d_ws;
  ushort_t* xT   = ws;                 // (B,T,C)  33,554,432
  ushort_t* Qt   = ws + 33554432;      // (B,T,D)  16,777,216
  ushort_t* KV   = ws + 50331648;      // (B,2D,S) 16,777,216  rows 0..511=Kd, 512..1023=V
  ushort_t* WtT  = ws + 67108864;      // (B,D,D)   4,194,304
  ushort_t* Wco  = ws + 71303168;      // (B,C,D)   8,388,608
  ushort_t* Wq_b = ws + 79691776;      //     524,288  (Wq,Wk,Wv,Wo contiguous)
  ushort_t* Wo_b = ws + 79691776 + 3 * 524288;
  float*    bkv  = (float*)(ws + 81788928);   // 1024 floats
  float2*   pstat = (float2*)(ws + 81790976); // 16*8*1024 float2 = 1 MB
  float*    stats = (float*)(ws + 82315264);  // 2048 floats

  dim3 blk(256);
  dim3 blk512(512);

  // 0. Weights fp32 -> bf16 (contiguous) + concat bias [bk;bv].
  convert4<<<dim3(2048, 4), blk, 0, stream>>>(Wq, Wk, Wv, Wo, Wq_b, D * Cc,
                                              bk, bv, bkv);

  // 1. xT = bf16(x^T) for all 16 batches (64x64 vectorized tiles).
  transpose_f32_bf16<<<dim3(T / 64, Cc / 64, 16), blk, 0, stream>>>(x, xT, Cc, T);

  // 2. Qt (T,D): M=T, N=D, K=C; bias bq by n.
  gemm256<2, 0, false><<<dim3(D / 256, T / 256, 16), blk512, 0, stream>>>(
      xT, (long)T * Cc, Wq_b, 0, Qt, (long)T * D, Cc, Cc, Cc, D, bq, 1.0f);
  // 3. KV (2D,S): M=2D ([Wk;Wv] contiguous), N=T, K=C; maxpool n-pairs,
  //    bias [bk;bv] by m.
  gemm256<1, 1, false><<<dim3(T / 256, 2 * D / 256, 16), blk512, 0, stream>>>(
      Wq_b + (long)D * Cc, 0, xT, (long)T * Cc, KV, (long)2 * D * S,
      Cc, Cc, Cc, S, bkv, 1.0f);

  // 4. WtT (D,D) = Kd x V^T : M=D (Kd rows), N=D (V rows), K=S.
  gemm256<0, 0, false><<<dim3(D / 256, D / 256, 16), blk512, 0, stream>>>(
      KV, (long)2 * D * S, KV + (long)D * S, (long)2 * D * S, WtT, (long)D * D,
      S, S, S, D, nullptr, 1.0f);
  // 5. Wco (C,D) = Wo x WtT^T / T : M=C, N=D, K=D.
  gemm256<0, 0, false><<<dim3(D / 256, Cc / 256, 16), blk512, 0, stream>>>(
      Wo_b, 0, WtT, (long)D * D, Wco, (long)Cc * D,
      D, D, D, D, nullptr, 1.0f / 2048.0f);

  // 6. y = Wco x Qt^T + bo -> d_out (fp32, (B,C,T)); fused BN partials.
  gemm256<1, 0, true, true><<<dim3(T / 256, Cc / 256, 16), blk512, 0, stream>>>(
      Wco, (long)Cc * D, Qt, (long)T * D, out, (long)Cc * T,
      D, D, D, T, bo, 1.0f, pstat);

  // 7. BN finalize (mean/rstd per channel) + apply + residual.
  bn_finalize<<<dim3(1024), dim3(64), 0, stream>>>(pstat, stats);
  bn_apply<<<dim3(16384), blk, 0, stream>>>(out, x, stats, gamma, beta);
}

// Round 4
// 528.543 us; speedup vs baseline: 1.3486x; 1.0126x over previous
//
#include <hip/hip_runtime.h>

typedef unsigned short ushort_t;
typedef __bf16 bf16x8 __attribute__((ext_vector_type(8)));
typedef float floatx4 __attribute__((ext_vector_type(4)));
typedef ushort_t ushortx8 __attribute__((ext_vector_type(8)));

#define BM 128
#define BN 128
#define BKK 64

__device__ __forceinline__ ushort_t f2bf(float f) {
  union { float f; unsigned int u; } c; c.f = f;
  unsigned int r = c.u + 0x7FFFu + ((c.u >> 16) & 1u);
  return (ushort_t)(r >> 16);
}

// Async 16B global->LDS (lane-contiguous LDS dest required: base + lane*16).
__device__ __forceinline__ void async16(const ushort_t* g, ushort_t* l) {
  __builtin_amdgcn_global_load_lds(
      (const __attribute__((address_space(1))) unsigned int*)g,
      (__attribute__((address_space(3))) unsigned int*)l, 16, 0, 0);
}

// ============================================================================
// 256x256 8-phase GEMM (m201 template: T2 LDS swizzle + T3/T4 counted vmcnt +
// T5 setprio). C[M,N] = A[M,K] x Bt[N,K], bf16 in, fp32 accum.
// 512 threads = 8 waves (2M x 4N); per-wave 128x64 out; BK=64, 2 K-tiles/iter.
// LDS 128 KiB: As/Bs[2][256][64]. Swizzle: 16B-block ^= (row&7), both sides.
// BIASM: 0 none, 1 bias[m], 2 bias[n].  POOLM: 0 none, 1 pool n-pairs,
// 2 pool m-pairs.  OUTF32: write float.  STATS: per-channel(m) sum/sumsq
// partials -> pstat[(z*gridDim.x+bx)*1024 + m] (float2), for fused BN stats.
// ============================================================================
template<int BIASM, int POOLM, bool OUTF32, bool STATS = false>
__global__ __launch_bounds__(512, 2)
void gemm256(const ushort_t* __restrict__ A, long aStr,
             const ushort_t* __restrict__ B, long bStr,
             void* __restrict__ Cp, long cStr,
             int K, int lda, int ldb, int ldc,
             const float* __restrict__ bias, float scale,
             float2* __restrict__ pstat = nullptr)
{
  __shared__ ushort_t As[2][256][64];
  __shared__ ushort_t Bs[2][256][64];
  __shared__ float2 part[4][256];   // STATS only: per-wn-wave channel partials

  A += (long)blockIdx.z * aStr;
  B += (long)blockIdx.z * bStr;
  float* Cf = (float*)Cp + (OUTF32 ? (long)blockIdx.z * cStr : 0);
  ushort_t* Cb = (ushort_t*)Cp + (OUTF32 ? 0 : (long)blockIdx.z * cStr);
  const int m0 = blockIdx.y * 256;
  const int n0 = blockIdx.x * 256;
  const int tid = threadIdx.x;
  const int lane = tid & 63;
  const int wid = tid >> 6;
  const int wm = wid >> 2;        // 0..1
  const int wn = wid & 3;         // 0..3
  const int l15 = lane & 15;
  const int lq  = lane >> 4;      // 0..3

  // Staging: thread t covers 16B block (srow, t&7) of a 64-row pass.
  // LDS dest is LINEAR (gload_lds constraint); source col is pre-swizzled so
  // physical block pb holds logical block pb ^ (row&7)  (involution).
  const int srow = tid >> 3;                         // 0..63
  const int scb  = (((tid & 7) ^ (srow & 7)) << 3);  // swizzled src col (bf16)
  const int dcb  = (tid & 7) << 3;                   // linear LDS dest col

  const ushort_t* gA = A + (long)(m0 + srow) * lda + scb;
  const ushort_t* gB = B + (long)(n0 + srow) * ldb + scb;

  // Read-side swizzled col offsets (bf16 units) for kk=0 / kk=1.
  // logical block = kk*4 + lq ; row&7 == l15&7 for all fragment rows.
  const int pb0 = ((lq ^ (l15 & 7)) << 3);
  const int pb1 = (((4 | lq) ^ (l15 & 7)) << 3);

  floatx4 acc[8][4];
#pragma unroll
  for (int i = 0; i < 8; ++i)
#pragma unroll
    for (int j = 0; j < 4; ++j)
#pragma unroll
      for (int r = 0; r < 4; ++r) acc[i][j][r] = 0.0f;

  bf16x8 aA[4][2], bB0[2][2], bB1[2][2];

  const int NT = K >> 6;   // K-tiles of 64
  const int NI = NT >> 1;  // iterations (2 tiles each)

#define STAGE_A(sl, hf, kt) do { \
    const ushort_t* _s = gA + (long)((hf) * 128) * lda + ((kt) << 6); \
    async16(_s,                  &As[sl][(hf)*128      + srow][dcb]); \
    async16(_s + (long)64 * lda, &As[sl][(hf)*128 + 64 + srow][dcb]); \
  } while (0)
#define STAGE_B(sl, hf, kt) do { \
    const ushort_t* _s = gB + (long)((hf) * 128) * ldb + ((kt) << 6); \
    async16(_s,                  &Bs[sl][(hf)*128      + srow][dcb]); \
    async16(_s + (long)64 * ldb, &Bs[sl][(hf)*128 + 64 + srow][dcb]); \
  } while (0)
#define LD_A(sl, mh) do { \
    _Pragma("unroll") for (int _i = 0; _i < 4; ++_i) { \
      const int _r = wm*128 + (mh)*64 + _i*16 + l15; \
      aA[_i][0] = *(const bf16x8*)&As[sl][_r][pb0]; \
      aA[_i][1] = *(const bf16x8*)&As[sl][_r][pb1]; } \
  } while (0)
#define LD_B(sl, nh, dst) do { \
    _Pragma("unroll") for (int _j = 0; _j < 2; ++_j) { \
      const int _r = wn*64 + (nh)*32 + _j*16 + l15; \
      dst[_j][0] = *(const bf16x8*)&Bs[sl][_r][pb0]; \
      dst[_j][1] = *(const bf16x8*)&Bs[sl][_r][pb1]; } \
  } while (0)
#define MMA(mh, nh, bfr) do { \
    __builtin_amdgcn_s_setprio(1); \
    _Pragma("unroll") for (int _i = 0; _i < 4; ++_i) \
    _Pragma("unroll") for (int _j = 0; _j < 2; ++_j) { \
      floatx4& _c = acc[(mh)*4 + _i][(nh)*2 + _j]; \
      _c = __builtin_amdgcn_mfma_f32_16x16x32_bf16(aA[_i][0], (bfr)[_j][0], _c, 0, 0, 0); \
      _c = __builtin_amdgcn_mfma_f32_16x16x32_bf16(aA[_i][1], (bfr)[_j][1], _c, 0, 0, 0); } \
    __builtin_amdgcn_s_setprio(0); \
  } while (0)
#define SBAR  __builtin_amdgcn_s_barrier()
#define LGKM0 asm volatile("s_waitcnt lgkmcnt(0)" ::: "memory")
#define VM4   asm volatile("s_waitcnt vmcnt(4)" ::: "memory")
#define VM0   asm volatile("s_waitcnt vmcnt(0)" ::: "memory")

  // Prologue: tile0 (4 halves) + A0(1), B1(1). vmcnt(4) leaves newest 2 halves
  // (4 loads) in flight; tile0 fully landed for phase 1.
  STAGE_A(0, 0, 0); STAGE_A(0, 1, 0); STAGE_B(0, 0, 0); STAGE_B(0, 1, 0);
  STAGE_A(1, 0, 1); STAGE_B(1, 1, 1);
  VM4; SBAR;

  // Quadrant order per tile: (0,0),(0,1),(1,1),(1,0) -> A read once/half,
  // both B halves stay live. Stage schedule (1 half/phase) derived from
  // per-region last-read times; waits only at phases 4 and 8 (counted).
  for (int i = 0; i < NI - 1; ++i) {
    const int t1 = 2*i + 1, t2 = 2*i + 2, t3 = 2*i + 3;
    // ph1: compute tile 2i quad(0,0); stage A1(2i+1)
    LD_A(0, 0); LD_B(0, 0, bB0); STAGE_A(1, 1, t1);
    SBAR; LGKM0; MMA(0, 0, bB0); SBAR;
    // ph2: quad(0,1); stage B0(2i+1)
    LD_B(0, 1, bB1); STAGE_B(1, 0, t1);
    SBAR; LGKM0; MMA(0, 1, bB1); SBAR;
    // ph3: quad(1,1); stage A0(2i+2)
    LD_A(0, 1); STAGE_A(0, 0, t2);
    SBAR; LGKM0; MMA(1, 1, bB1); SBAR;
    // ph4: quad(1,0); stage B1(2i+2); wait -> tile 2i+1 resident
    STAGE_B(0, 1, t2);
    SBAR; LGKM0; MMA(1, 0, bB0); VM4; SBAR;
    // ph5: tile 2i+1 quad(0,0); stage A1(2i+2)
    LD_A(1, 0); LD_B(1, 0, bB0); STAGE_A(0, 1, t2);
    SBAR; LGKM0; MMA(0, 0, bB0); SBAR;
    // ph6: quad(0,1); stage B0(2i+2)
    LD_B(1, 1, bB1); STAGE_B(0, 0, t2);
    SBAR; LGKM0; MMA(0, 1, bB1); SBAR;
    // ph7: quad(1,1); stage A0(2i+3)
    LD_A(1, 1); STAGE_A(1, 0, t3);
    SBAR; LGKM0; MMA(1, 1, bB1); SBAR;
    // ph8: quad(1,0); stage B1(2i+3); wait -> tile 2i+2 resident
    STAGE_B(1, 1, t3);
    SBAR; LGKM0; MMA(1, 0, bB0); VM4; SBAR;
  }
  // Peeled final iteration (tiles NT-2, NT-1): only the two mandatory stages,
  // full drain at ph4.
  {
    const int t1 = NT - 1;
    LD_A(0, 0); LD_B(0, 0, bB0); STAGE_A(1, 1, t1);
    SBAR; LGKM0; MMA(0, 0, bB0); SBAR;
    LD_B(0, 1, bB1); STAGE_B(1, 0, t1);
    SBAR; LGKM0; MMA(0, 1, bB1); SBAR;
    LD_A(0, 1);
    SBAR; LGKM0; MMA(1, 1, bB1); SBAR;
    SBAR; LGKM0; MMA(1, 0, bB0); VM0; SBAR;
    LD_A(1, 0); LD_B(1, 0, bB0);
    SBAR; LGKM0; MMA(0, 0, bB0); SBAR;
    LD_B(1, 1, bB1);
    SBAR; LGKM0; MMA(0, 1, bB1); SBAR;
    LD_A(1, 1);
    SBAR; LGKM0; MMA(1, 1, bB1); SBAR;
    LGKM0; MMA(1, 0, bB0);
  }
#undef STAGE_A
#undef STAGE_B
#undef LD_A
#undef LD_B
#undef MMA
#undef SBAR
#undef LGKM0
#undef VM4
#undef VM0

  // Epilogue. acc[mi][nj]: m-off = (mi>>2)*64 + (mi&3)*16 ; n-off = (nj>>1)*32
  // + (nj&1)*16 (quadrant decomposition).
#pragma unroll
  for (int mi = 0; mi < 8; ++mi) {
    const int mbase = m0 + wm*128 + (mi >> 2)*64 + (mi & 3)*16 + lq*4;
    float ss[4], ss2[4];
    if (STATS) {
#pragma unroll
      for (int r = 0; r < 4; ++r) { ss[r] = 0.0f; ss2[r] = 0.0f; }
    }
#pragma unroll
    for (int nj = 0; nj < 4; ++nj) {
      const int n = n0 + wn*64 + (nj >> 1)*32 + (nj & 1)*16 + l15;
      float v[4];
#pragma unroll
      for (int r = 0; r < 4; ++r) {
        v[r] = acc[mi][nj][r] * scale;
        if (BIASM == 1) v[r] += bias[mbase + r];
      }
      if (BIASM == 2) {
        const float bn_ = bias[n];
#pragma unroll
        for (int r = 0; r < 4; ++r) v[r] += bn_;
      }
      if (STATS) {
#pragma unroll
        for (int r = 0; r < 4; ++r) { ss[r] += v[r]; ss2[r] += v[r] * v[r]; }
      }
      if (POOLM == 0) {
#pragma unroll
        for (int r = 0; r < 4; ++r) {
          if (OUTF32) Cf[(long)(mbase + r) * ldc + n] = v[r];
          else        Cb[(long)(mbase + r) * ldc + n] = f2bf(v[r]);
        }
      } else if (POOLM == 1) {
#pragma unroll
        for (int r = 0; r < 4; ++r) {
          float o = __shfl_xor(v[r], 1);
          float w = fmaxf(v[r], o);
          if ((lane & 1) == 0) {
            if (OUTF32) Cf[(long)(mbase + r) * ldc + (n >> 1)] = w;
            else        Cb[(long)(mbase + r) * ldc + (n >> 1)] = f2bf(w);
          }
        }
      } else {  // POOLM == 2
        float w0 = fmaxf(v[0], v[1]);
        float w1 = fmaxf(v[2], v[3]);
        const int mh = mbase >> 1;
        if (OUTF32) {
          Cf[(long)mh * ldc + n] = w0;
          Cf[(long)(mh + 1) * ldc + n] = w1;
        } else {
          Cb[(long)mh * ldc + n] = f2bf(w0);
          Cb[(long)(mh + 1) * ldc + n] = f2bf(w1);
        }
      }
    }
    if (STATS) {
      // Reduce over the 16 l15 lanes (same lq => same channels, different n).
#pragma unroll
      for (int o = 1; o < 16; o <<= 1) {
#pragma unroll
        for (int r = 0; r < 4; ++r) {
          ss[r]  += __shfl_xor(ss[r],  o);
          ss2[r] += __shfl_xor(ss2[r], o);
        }
      }
      if (l15 == 0) {
        const int chb = wm*128 + (mi >> 2)*64 + (mi & 3)*16 + lq*4;
#pragma unroll
        for (int r = 0; r < 4; ++r) part[wn][chb + r] = make_float2(ss[r], ss2[r]);
      }
    }
  }
  if (STATS) {
    __syncthreads();
    if (tid < 256) {
      float2 p0 = part[0][tid], p1 = part[1][tid], p2 = part[2][tid], p3 = part[3][tid];
      float2 p = make_float2(p0.x + p1.x + p2.x + p3.x, p0.y + p1.y + p2.y + p3.y);
      pstat[((long)blockIdx.z * gridDim.x + blockIdx.x) * 1024 + m0 + tid] = p;
    }
  }
}

// ============================================================================
// 128x128 GEMM (m97 structure) for small grids: 256 threads = 4 waves, BK=64,
// 32 KiB LDS -> ~3 blocks/CU. Used where 256^2 tiles can't fill the machine.
// C[M,N] = A[M,K] x Bt[N,K] bf16, fp32 accum. Same BIASM/POOLM/OUTF32 flags.
// ============================================================================
template<int BIASM, int POOLM, bool OUTF32>
__global__ __launch_bounds__(256)
void gemm_bt(const ushort_t* __restrict__ A, long aStr,
             const ushort_t* __restrict__ B, long bStr,
             void* __restrict__ Cp, long cStr,
             int K, int lda, int ldb, int ldc,
             const float* __restrict__ bias, float scale)
{
  __shared__ ushort_t As[BM][BKK];
  __shared__ ushort_t Bs[BN][BKK];
  A += (long)blockIdx.z * aStr;
  B += (long)blockIdx.z * bStr;
  float* Cf = (float*)Cp + (OUTF32 ? (long)blockIdx.z * cStr : 0);
  ushort_t* Cb = (ushort_t*)Cp + (OUTF32 ? 0 : (long)blockIdx.z * cStr);
  const int m0 = blockIdx.y * BM;
  const int n0 = blockIdx.x * BN;
  const int tid = threadIdx.x;
  const int lane = tid & 63;
  const int wm = (tid >> 7) & 1;
  const int wn = (tid >> 6) & 1;
  const int ar = tid >> 3;         // staging row 0..31
  const int ac = (tid & 7) * 8;    // staging col (8 bf16 = 16B per thread)

  floatx4 acc[4][4];
#pragma unroll
  for (int i = 0; i < 4; ++i)
#pragma unroll
    for (int j = 0; j < 4; ++j)
#pragma unroll
      for (int r = 0; r < 4; ++r) acc[i][j][r] = 0.0f;

  const int q8 = (lane >> 4) * 8;
  const int l15 = lane & 15;

  const ushort_t* gA = &A[(long)(m0 + ar) * lda + ac];
  const ushort_t* gB = &B[(long)(n0 + ar) * ldb + ac];
  const long aRow32 = (long)32 * lda;
  const long bRow32 = (long)32 * ldb;

  for (int k0 = 0; k0 < K; k0 += BKK) {
#pragma unroll
    for (int p = 0; p < 4; ++p)
      async16(gA + p * aRow32 + k0, &As[p * 32 + ar][ac]);
#pragma unroll
    for (int p = 0; p < 4; ++p)
      async16(gB + p * bRow32 + k0, &Bs[p * 32 + ar][ac]);
    __syncthreads();
#pragma unroll
    for (int kk = 0; kk < 2; ++kk) {
      const int kr = kk * 32 + q8;
      bf16x8 af[4], bfr[4];
#pragma unroll
      for (int i = 0; i < 4; ++i) {
        af[i]  = *(const bf16x8*)(&As[wm * 64 + i * 16 + l15][kr]);
        bfr[i] = *(const bf16x8*)(&Bs[wn * 64 + i * 16 + l15][kr]);
      }
#pragma unroll
      for (int i = 0; i < 4; ++i)
#pragma unroll
        for (int j = 0; j < 4; ++j)
          acc[i][j] = __builtin_amdgcn_mfma_f32_16x16x32_bf16(af[i], bfr[j], acc[i][j], 0, 0, 0);
    }
    __syncthreads();
  }

#pragma unroll
  for (int i = 0; i < 4; ++i) {
    const int mbase = m0 + wm * 64 + i * 16 + (lane >> 4) * 4;
#pragma unroll
    for (int j = 0; j < 4; ++j) {
      const int n = n0 + wn * 64 + j * 16 + l15;
      float v[4];
#pragma unroll
      for (int r = 0; r < 4; ++r) {
        v[r] = acc[i][j][r] * scale;
        if (BIASM == 1) v[r] += bias[mbase + r];
      }
      if (BIASM == 2) {
        const float bn_ = bias[n];
#pragma unroll
        for (int r = 0; r < 4; ++r) v[r] += bn_;
      }
      if (POOLM == 0) {
#pragma unroll
        for (int r = 0; r < 4; ++r) {
          if (OUTF32) Cf[(long)(mbase + r) * ldc + n] = v[r];
          else        Cb[(long)(mbase + r) * ldc + n] = f2bf(v[r]);
        }
      } else if (POOLM == 1) {
#pragma unroll
        for (int r = 0; r < 4; ++r) {
          float o = __shfl_xor(v[r], 1);
          float w = fmaxf(v[r], o);
          if ((lane & 1) == 0) {
            if (OUTF32) Cf[(long)(mbase + r) * ldc + (n >> 1)] = w;
            else        Cb[(long)(mbase + r) * ldc + (n >> 1)] = f2bf(w);
          }
        }
      } else {  // POOLM == 2
        float w0 = fmaxf(v[0], v[1]);
        float w1 = fmaxf(v[2], v[3]);
        const int mh = mbase >> 1;
        if (OUTF32) {
          Cf[(long)mh * ldc + n] = w0;
          Cf[(long)(mh + 1) * ldc + n] = w1;
        } else {
          Cb[(long)mh * ldc + n] = f2bf(w0);
          Cb[(long)(mh + 1) * ldc + n] = f2bf(w1);
        }
      }
    }
  }
}

// dst[t][c] = bf16(src[c][t]) per batch z. src (Rr=C rows, Cl=T cols) fp32.
// 64x64 tiles; float4 global reads, ushort8 global writes.
__global__ __launch_bounds__(256)
void transpose_f32_bf16(const float* __restrict__ src, ushort_t* __restrict__ dst,
                        int Rr, int Cl)
{
  __shared__ ushort_t tileT[64][72];
  const long boff = (long)blockIdx.z * Rr * Cl;
  const int t0 = blockIdx.x * 64;   // col tile (contiguous dim of src)
  const int r0 = blockIdx.y * 64;   // row tile (contiguous dim of dst)
  const int tx = threadIdx.x & 15;
  const int ty = threadIdx.x >> 4;
#pragma unroll
  for (int i = 0; i < 4; ++i) {
    const int c = ty + 16 * i;      // tile row index (src row r0+c)
    floatx4 v = *(const floatx4*)&src[boff + (long)(r0 + c) * Cl + t0 + 4 * tx];
#pragma unroll
    for (int j = 0; j < 4; ++j) tileT[4 * tx + j][c] = f2bf(v[j]);
  }
  __syncthreads();
  const int cx = threadIdx.x & 7;
  const int tw = threadIdx.x >> 3;
#pragma unroll
  for (int i = 0; i < 2; ++i) {
    const int t = tw + 32 * i;
    ushortx8 w = *(const ushortx8*)&tileT[t][8 * cx];
    *(ushortx8*)&dst[boff + (long)(t0 + t) * Rr + r0 + 8 * cx] = w;
  }
}

// Convert 4 equal-size fp32 weight buffers to contiguous bf16 regions, and
// build concatenated bias bkv[1024] = {bk, bv}.
__global__ __launch_bounds__(256)
void convert4(const float* __restrict__ a, const float* __restrict__ b,
              const float* __restrict__ c, const float* __restrict__ d,
              ushort_t* __restrict__ dst, int n,
              const float* __restrict__ bk, const float* __restrict__ bv,
              float* __restrict__ bkv)
{
  const float* srcs[4] = {a, b, c, d};
  const float* s = srcs[blockIdx.y];
  int i = blockIdx.x * 256 + threadIdx.x;
  if (i < n) dst[(long)blockIdx.y * n + i] = f2bf(s[i]);
  if (blockIdx.y == 0 && blockIdx.x == 0) {
    for (int j = threadIdx.x; j < 1024; j += 256)
      bkv[j] = (j < 512) ? bk[j] : bv[j - 512];
  }
}

// In-place: y = gamma*(y-mean)*rstd + beta + x ; one block per (b,c) row.
// BN finalize folded in: each block reduces the 128 L2-hot pstat partials for
// its channel (threads 0..127), then applies. float4 streaming.
__global__ __launch_bounds__(256)
void bn_apply(float* __restrict__ y, const float* __restrict__ x,
              const float2* __restrict__ pstat, const float* __restrict__ gamma,
              const float* __restrict__ beta)
{
  const int bc = blockIdx.x;
  const int c = bc & 1023;
  float s = 0.0f, s2 = 0.0f;
  if (threadIdx.x < 128) {
    float2 p = pstat[(long)threadIdx.x * 1024 + c];
    s = p.x; s2 = p.y;
  }
#pragma unroll
  for (int o = 32; o > 0; o >>= 1) { s += __shfl_down(s, o); s2 += __shfl_down(s2, o); }
  __shared__ float red[4];
  __shared__ float smv[2];
  const int w = threadIdx.x >> 6;
  if ((threadIdx.x & 63) == 0 && w < 2) { red[w] = s; red[2 + w] = s2; }
  __syncthreads();
  if (threadIdx.x == 0) {
    float ts = red[0] + red[1], ts2 = red[2] + red[3];
    const float inv = 1.0f / (16.0f * 2048.0f);
    float mean = ts * inv;
    float var = ts2 * inv - mean * mean;
    smv[0] = mean;
    smv[1] = rsqrtf(var + 1e-5f);
  }
  __syncthreads();
  const float mean = smv[0];
  const float g = gamma[c] * smv[1];
  const float bt = beta[c];
  const long off = (long)bc * 2048;
  floatx4* yp = (floatx4*)(y + off);
  const floatx4* xp = (const floatx4*)(x + off);
  for (int t = threadIdx.x; t < 512; t += 256) {
    floatx4 v = yp[t];
    floatx4 xv = xp[t];
#pragma unroll
    for (int r = 0; r < 4; ++r) v[r] = (v[r] - mean) * g + bt + xv[r];
    yp[t] = v;
  }
}

extern "C" void kernel_launch(void* const* d_in, const int* in_sizes, int n_in,
                              void* d_out, int out_size, void* d_ws, size_t ws_size,
                              hipStream_t stream) {
  (void)in_sizes; (void)n_in; (void)out_size; (void)ws_size;
  const float* x  = (const float*)d_in[0];
  const float* Wq = (const float*)d_in[1];
  const float* bq = (const float*)d_in[2];
  const float* Wk = (const float*)d_in[3];
  const float* bk = (const float*)d_in[4];
  const float* Wv = (const float*)d_in[5];
  const float* bv = (const float*)d_in[6];
  const float* Wo = (const float*)d_in[7];
  const float* bo = (const float*)d_in[8];
  const float* gamma = (const float*)d_in[9];
  const float* beta  = (const float*)d_in[10];
  float* out = (float*)d_out;

  const int Cc = 1024, T = 2048, D = 512, S = 1024;

  // Full algebraic chain (softmax-free attention):
  //   y = Wo (V Kd^T) Qt^T / T + bo  with K/V maxpooled.
  //   WtT = Kd V^T ; Wco = Wo WtT^T / T ; y = Wco Qt^T + bo.
  // BN stats fused into the y-GEMM epilogue (partials -> bn_apply reduce).
  ushort_t* ws   = (ushort_t*)d_ws;
  ushort_t* xT   = ws;                 // (B,T,C)  33,554,432
  ushort_t* Qt   = ws + 33554432;      // (B,T,D)  16,777,216
  ushort_t* KV   = ws + 50331648;      // (B,2D,S) 16,777,216  rows 0..511=Kd, 512..1023=V
  ushort_t* WtT  = ws + 67108864;      // (B,D,D)   4,194,304
  ushort_t* Wco  = ws + 71303168;      // (B,C,D)   8,388,608
  ushort_t* Wq_b = ws + 79691776;      //     524,288  (Wq,Wk,Wv,Wo contiguous)
  ushort_t* Wo_b = ws + 79691776 + 3 * 524288;
  float*    bkv  = (float*)(ws + 81788928);   // 1024 floats
  float2*   pstat = (float2*)(ws + 81790976); // 16*8*1024 float2 = 1 MB

  dim3 blk(256);
  dim3 blk512(512);

  // 0. Weights fp32 -> bf16 (contiguous) + concat bias [bk;bv].
  convert4<<<dim3(2048, 4), blk, 0, stream>>>(Wq, Wk, Wv, Wo, Wq_b, D * Cc,
                                              bk, bv, bkv);

  // 1. xT = bf16(x^T) for all 16 batches (64x64 vectorized tiles).
  transpose_f32_bf16<<<dim3(T / 64, Cc / 64, 16), blk, 0, stream>>>(x, xT, Cc, T);

  // 2. Qt (T,D): M=T, N=D, K=C; bias bq by n.
  gemm256<2, 0, false><<<dim3(D / 256, T / 256, 16), blk512, 0, stream>>>(
      xT, (long)T * Cc, Wq_b, 0, Qt, (long)T * D, Cc, Cc, Cc, D, bq, 1.0f);
  // 3. KV (2D,S): M=2D ([Wk;Wv] contiguous), N=T, K=C; maxpool n-pairs,
  //    bias [bk;bv] by m.
  gemm256<1, 1, false><<<dim3(T / 256, 2 * D / 256, 16), blk512, 0, stream>>>(
      Wq_b + (long)D * Cc, 0, xT, (long)T * Cc, KV, (long)2 * D * S,
      Cc, Cc, Cc, S, bkv, 1.0f);

  // 4. WtT (D,D) = Kd x V^T : M=D, N=D, K=S.  128^2 tiles -> 256 blocks
  //    (256^2 gave only 64 blocks = 75% of CUs idle).
  gemm_bt<0, 0, false><<<dim3(D / 128, D / 128, 16), blk, 0, stream>>>(
      KV, (long)2 * D * S, KV + (long)D * S, (long)2 * D * S, WtT, (long)D * D,
      S, S, S, D, nullptr, 1.0f);
  // 5. Wco (C,D) = Wo x WtT^T / T : M=C, N=D, K=D.  128^2 tiles -> 512 blocks.
  gemm_bt<0, 0, false><<<dim3(D / 128, Cc / 128, 16), blk, 0, stream>>>(
      Wo_b, 0, WtT, (long)D * D, Wco, (long)Cc * D,
      D, D, D, D, nullptr, 1.0f / 2048.0f);

  // 6. y = Wco x Qt^T + bo -> d_out (fp32, (B,C,T)); fused BN partials.
  gemm256<1, 0, true, true><<<dim3(T / 256, Cc / 256, 16), blk512, 0, stream>>>(
      Wco, (long)Cc * D, Qt, (long)T * D, out, (long)Cc * T,
      D, D, D, T, bo, 1.0f, pstat);

  // 7. BN finalize (folded) + apply + residual.
  bn_apply<<<dim3(16384), blk, 0, stream>>>(out, x, pstat, gamma, beta);
}

// Round 5
// 517.434 us; speedup vs baseline: 1.3776x; 1.0215x over previous
//
#include <hip/hip_runtime.h>

typedef unsigned short ushort_t;
typedef __bf16 bf16x8 __attribute__((ext_vector_type(8)));
typedef float floatx4 __attribute__((ext_vector_type(4)));
typedef ushort_t ushortx8 __attribute__((ext_vector_type(8)));
typedef ushort_t ushortx4 __attribute__((ext_vector_type(4)));

#define BM 128
#define BN 128
#define BKK 64

__device__ __forceinline__ ushort_t f2bf(float f) {
  union { float f; unsigned int u; } c; c.f = f;
  unsigned int r = c.u + 0x7FFFu + ((c.u >> 16) & 1u);
  return (ushort_t)(r >> 16);
}

__device__ __forceinline__ float bf2f(ushort_t u) {
  union { unsigned int u; float f; } c; c.u = ((unsigned int)u) << 16;
  return c.f;
}

// Async 16B global->LDS (lane-contiguous LDS dest required: base + lane*16).
__device__ __forceinline__ void async16(const ushort_t* g, ushort_t* l) {
  __builtin_amdgcn_global_load_lds(
      (const __attribute__((address_space(1))) unsigned int*)g,
      (__attribute__((address_space(3))) unsigned int*)l, 16, 0, 0);
}

// ============================================================================
// Shared 256x256 8-phase K-loop core (m201 template: T2 LDS swizzle + T3/T4
// counted vmcnt + T5 setprio). gA/gB pre-offset to (m0+srow)*ld + scb.
// Accumulates C[256,256] quadrants into acc[8][4] (fp32).
// ============================================================================
__device__ __forceinline__ void gemm_core(
    const ushort_t* __restrict__ gA, const ushort_t* __restrict__ gB,
    int lda, int ldb, int K,
    ushort_t (&As)[2][256][64], ushort_t (&Bs)[2][256][64],
    const int srow, const int dcb, const int wm, const int wn,
    const int l15, const int pb0, const int pb1,
    floatx4 (&acc)[8][4])
{
  bf16x8 aA[4][2], bB0[2][2], bB1[2][2];
  const int NT = K >> 6;   // K-tiles of 64
  const int NI = NT >> 1;  // iterations (2 tiles each)

#define STAGE_A(sl, hf, kt) do { \
    const ushort_t* _s = gA + (long)((hf) * 128) * lda + ((kt) << 6); \
    async16(_s,                  &As[sl][(hf)*128      + srow][dcb]); \
    async16(_s + (long)64 * lda, &As[sl][(hf)*128 + 64 + srow][dcb]); \
  } while (0)
#define STAGE_B(sl, hf, kt) do { \
    const ushort_t* _s = gB + (long)((hf) * 128) * ldb + ((kt) << 6); \
    async16(_s,                  &Bs[sl][(hf)*128      + srow][dcb]); \
    async16(_s + (long)64 * ldb, &Bs[sl][(hf)*128 + 64 + srow][dcb]); \
  } while (0)
#define LD_A(sl, mh) do { \
    _Pragma("unroll") for (int _i = 0; _i < 4; ++_i) { \
      const int _r = wm*128 + (mh)*64 + _i*16 + l15; \
      aA[_i][0] = *(const bf16x8*)&As[sl][_r][pb0]; \
      aA[_i][1] = *(const bf16x8*)&As[sl][_r][pb1]; } \
  } while (0)
#define LD_B(sl, nh, dst) do { \
    _Pragma("unroll") for (int _j = 0; _j < 2; ++_j) { \
      const int _r = wn*64 + (nh)*32 + _j*16 + l15; \
      dst[_j][0] = *(const bf16x8*)&Bs[sl][_r][pb0]; \
      dst[_j][1] = *(const bf16x8*)&Bs[sl][_r][pb1]; } \
  } while (0)
#define MMA(mh, nh, bfr) do { \
    __builtin_amdgcn_s_setprio(1); \
    _Pragma("unroll") for (int _i = 0; _i < 4; ++_i) \
    _Pragma("unroll") for (int _j = 0; _j < 2; ++_j) { \
      floatx4& _c = acc[(mh)*4 + _i][(nh)*2 + _j]; \
      _c = __builtin_amdgcn_mfma_f32_16x16x32_bf16(aA[_i][0], (bfr)[_j][0], _c, 0, 0, 0); \
      _c = __builtin_amdgcn_mfma_f32_16x16x32_bf16(aA[_i][1], (bfr)[_j][1], _c, 0, 0, 0); } \
    __builtin_amdgcn_s_setprio(0); \
  } while (0)
#define SBAR  __builtin_amdgcn_s_barrier()
#define LGKM0 asm volatile("s_waitcnt lgkmcnt(0)" ::: "memory")
#define VM4   asm volatile("s_waitcnt vmcnt(4)" ::: "memory")
#define VM0   asm volatile("s_waitcnt vmcnt(0)" ::: "memory")

  // Prologue: tile0 (4 halves) + A0(1), B1(1).
  STAGE_A(0, 0, 0); STAGE_A(0, 1, 0); STAGE_B(0, 0, 0); STAGE_B(0, 1, 0);
  STAGE_A(1, 0, 1); STAGE_B(1, 1, 1);
  VM4; SBAR;

  for (int i = 0; i < NI - 1; ++i) {
    const int t1 = 2*i + 1, t2 = 2*i + 2, t3 = 2*i + 3;
    LD_A(0, 0); LD_B(0, 0, bB0); STAGE_A(1, 1, t1);
    SBAR; LGKM0; MMA(0, 0, bB0); SBAR;
    LD_B(0, 1, bB1); STAGE_B(1, 0, t1);
    SBAR; LGKM0; MMA(0, 1, bB1); SBAR;
    LD_A(0, 1); STAGE_A(0, 0, t2);
    SBAR; LGKM0; MMA(1, 1, bB1); SBAR;
    STAGE_B(0, 1, t2);
    SBAR; LGKM0; MMA(1, 0, bB0); VM4; SBAR;
    LD_A(1, 0); LD_B(1, 0, bB0); STAGE_A(0, 1, t2);
    SBAR; LGKM0; MMA(0, 0, bB0); SBAR;
    LD_B(1, 1, bB1); STAGE_B(0, 0, t2);
    SBAR; LGKM0; MMA(0, 1, bB1); SBAR;
    LD_A(1, 1); STAGE_A(1, 0, t3);
    SBAR; LGKM0; MMA(1, 1, bB1); SBAR;
    STAGE_B(1, 1, t3);
    SBAR; LGKM0; MMA(1, 0, bB0); VM4; SBAR;
  }
  // Peeled final iteration.
  {
    const int t1 = NT - 1;
    LD_A(0, 0); LD_B(0, 0, bB0); STAGE_A(1, 1, t1);
    SBAR; LGKM0; MMA(0, 0, bB0); SBAR;
    LD_B(0, 1, bB1); STAGE_B(1, 0, t1);
    SBAR; LGKM0; MMA(0, 1, bB1); SBAR;
    LD_A(0, 1);
    SBAR; LGKM0; MMA(1, 1, bB1); SBAR;
    SBAR; LGKM0; MMA(1, 0, bB0); VM0; SBAR;
    LD_A(1, 0); LD_B(1, 0, bB0);
    SBAR; LGKM0; MMA(0, 0, bB0); SBAR;
    LD_B(1, 1, bB1);
    SBAR; LGKM0; MMA(0, 1, bB1); SBAR;
    LD_A(1, 1);
    SBAR; LGKM0; MMA(1, 1, bB1); SBAR;
    LGKM0; MMA(1, 0, bB0);
  }
#undef STAGE_A
#undef STAGE_B
#undef LD_A
#undef LD_B
#undef MMA
#undef SBAR
#undef LGKM0
#undef VM4
#undef VM0
}

// ============================================================================
// Generic 256^2 GEMM wrapper. BIASM: 0 none, 1 bias[m], 2 bias[n].
// POOLM: 0 none, 1 pool n-pairs, 2 pool m-pairs. OUTF32: write float.
// STATS: per-channel(m) sum/sumsq partials -> pstat (float2).
// ============================================================================
template<int BIASM, int POOLM, bool OUTF32, bool STATS = false>
__global__ __launch_bounds__(512, 2)
void gemm256(const ushort_t* __restrict__ A, long aStr,
             const ushort_t* __restrict__ B, long bStr,
             void* __restrict__ Cp, long cStr,
             int K, int lda, int ldb, int ldc,
             const float* __restrict__ bias, float scale,
             float2* __restrict__ pstat = nullptr)
{
  __shared__ ushort_t As[2][256][64];
  __shared__ ushort_t Bs[2][256][64];
  __shared__ float2 part[4][256];

  A += (long)blockIdx.z * aStr;
  B += (long)blockIdx.z * bStr;
  float* Cf = (float*)Cp + (OUTF32 ? (long)blockIdx.z * cStr : 0);
  ushort_t* Cb = (ushort_t*)Cp + (OUTF32 ? 0 : (long)blockIdx.z * cStr);
  const int m0 = blockIdx.y * 256;
  const int n0 = blockIdx.x * 256;
  const int tid = threadIdx.x;
  const int lane = tid & 63;
  const int wid = tid >> 6;
  const int wm = wid >> 2;
  const int wn = wid & 3;
  const int l15 = lane & 15;
  const int lq  = lane >> 4;
  const int srow = tid >> 3;
  const int scb  = (((tid & 7) ^ (srow & 7)) << 3);
  const int dcb  = (tid & 7) << 3;
  const int pb0 = ((lq ^ (l15 & 7)) << 3);
  const int pb1 = (((4 | lq) ^ (l15 & 7)) << 3);

  const ushort_t* gA = A + (long)(m0 + srow) * lda + scb;
  const ushort_t* gB = B + (long)(n0 + srow) * ldb + scb;

  floatx4 acc[8][4];
#pragma unroll
  for (int i = 0; i < 8; ++i)
#pragma unroll
    for (int j = 0; j < 4; ++j)
#pragma unroll
      for (int r = 0; r < 4; ++r) acc[i][j][r] = 0.0f;

  gemm_core(gA, gB, lda, ldb, K, As, Bs, srow, dcb, wm, wn, l15, pb0, pb1, acc);

#pragma unroll
  for (int mi = 0; mi < 8; ++mi) {
    const int mbase = m0 + wm*128 + (mi >> 2)*64 + (mi & 3)*16 + lq*4;
    float ss[4], ss2[4];
    if (STATS) {
#pragma unroll
      for (int r = 0; r < 4; ++r) { ss[r] = 0.0f; ss2[r] = 0.0f; }
    }
#pragma unroll
    for (int nj = 0; nj < 4; ++nj) {
      const int n = n0 + wn*64 + (nj >> 1)*32 + (nj & 1)*16 + l15;
      float v[4];
#pragma unroll
      for (int r = 0; r < 4; ++r) {
        v[r] = acc[mi][nj][r] * scale;
        if (BIASM == 1) v[r] += bias[mbase + r];
      }
      if (BIASM == 2) {
        const float bn_ = bias[n];
#pragma unroll
        for (int r = 0; r < 4; ++r) v[r] += bn_;
      }
      if (STATS) {
#pragma unroll
        for (int r = 0; r < 4; ++r) { ss[r] += v[r]; ss2[r] += v[r] * v[r]; }
      }
      if (POOLM == 0) {
#pragma unroll
        for (int r = 0; r < 4; ++r) {
          if (OUTF32) Cf[(long)(mbase + r) * ldc + n] = v[r];
          else        Cb[(long)(mbase + r) * ldc + n] = f2bf(v[r]);
        }
      } else if (POOLM == 1) {
#pragma unroll
        for (int r = 0; r < 4; ++r) {
          float o = __shfl_xor(v[r], 1);
          float w = fmaxf(v[r], o);
          if ((lane & 1) == 0) {
            if (OUTF32) Cf[(long)(mbase + r) * ldc + (n >> 1)] = w;
            else        Cb[(long)(mbase + r) * ldc + (n >> 1)] = f2bf(w);
          }
        }
      } else {
        float w0 = fmaxf(v[0], v[1]);
        float w1 = fmaxf(v[2], v[3]);
        const int mh = mbase >> 1;
        if (OUTF32) {
          Cf[(long)mh * ldc + n] = w0;
          Cf[(long)(mh + 1) * ldc + n] = w1;
        } else {
          Cb[(long)mh * ldc + n] = f2bf(w0);
          Cb[(long)(mh + 1) * ldc + n] = f2bf(w1);
        }
      }
    }
    if (STATS) {
#pragma unroll
      for (int o = 1; o < 16; o <<= 1) {
#pragma unroll
        for (int r = 0; r < 4; ++r) {
          ss[r]  += __shfl_xor(ss[r],  o);
          ss2[r] += __shfl_xor(ss2[r], o);
        }
      }
      if (l15 == 0) {
        const int chb = wm*128 + (mi >> 2)*64 + (mi & 3)*16 + lq*4;
#pragma unroll
        for (int r = 0; r < 4; ++r) part[wn][chb + r] = make_float2(ss[r], ss2[r]);
      }
    }
  }
  if (STATS) {
    __syncthreads();
    if (tid < 256) {
      float2 p0 = part[0][tid], p1 = part[1][tid], p2 = part[2][tid], p3 = part[3][tid];
      float2 p = make_float2(p0.x + p1.x + p2.x + p3.x, p0.y + p1.y + p2.y + p3.y);
      pstat[((long)blockIdx.z * gridDim.x + blockIdx.x) * 1024 + m0 + tid] = p;
    }
  }
}

// ============================================================================
// Fused Q + KV projection: one dispatch, uniform per-block work (256x256xK=1024).
// Flattened tile id: id<16 -> Q-mode (M=T tiles, N=D), else KV-mode (M=2D, N=T,
// pool n-pairs). 48 tiles/batch * 16 = 768 blocks = 3 clean rounds of 256 CUs.
// ============================================================================
__global__ __launch_bounds__(512, 2)
void gemm_qkv(const ushort_t* __restrict__ xT, const ushort_t* __restrict__ Wq_b,
              ushort_t* __restrict__ Qt, ushort_t* __restrict__ KV,
              const float* __restrict__ bq, const float* __restrict__ bkv)
{
  __shared__ ushort_t As[2][256][64];
  __shared__ ushort_t Bs[2][256][64];

  const int z = blockIdx.z;
  const int id = blockIdx.x;
  const bool isQ = id < 16;
  const int bx = isQ ? (id & 1) : ((id - 16) & 7);
  const int by = isQ ? (id >> 1) : ((id - 16) >> 3);
  const int m0 = by * 256;
  const int n0 = bx * 256;
  const ushort_t* xz = xT + (long)z * 2048 * 1024;
  const ushort_t* Abase = isQ ? xz : (Wq_b + 512 * 1024);  // Wkv rows follow Wq
  const ushort_t* Bbase = isQ ? Wq_b : xz;

  const int tid = threadIdx.x;
  const int lane = tid & 63;
  const int wid = tid >> 6;
  const int wm = wid >> 2;
  const int wn = wid & 3;
  const int l15 = lane & 15;
  const int lq  = lane >> 4;
  const int srow = tid >> 3;
  const int scb  = (((tid & 7) ^ (srow & 7)) << 3);
  const int dcb  = (tid & 7) << 3;
  const int pb0 = ((lq ^ (l15 & 7)) << 3);
  const int pb1 = (((4 | lq) ^ (l15 & 7)) << 3);

  const ushort_t* gA = Abase + (long)(m0 + srow) * 1024 + scb;
  const ushort_t* gB = Bbase + (long)(n0 + srow) * 1024 + scb;

  floatx4 acc[8][4];
#pragma unroll
  for (int i = 0; i < 8; ++i)
#pragma unroll
    for (int j = 0; j < 4; ++j)
#pragma unroll
      for (int r = 0; r < 4; ++r) acc[i][j][r] = 0.0f;

  gemm_core(gA, gB, 1024, 1024, 1024, As, Bs, srow, dcb, wm, wn, l15, pb0, pb1, acc);

  if (isQ) {
    // Qt (T,D) row-major, bias bq[n].
    ushort_t* Cq = Qt + (long)z * 2048 * 512;
#pragma unroll
    for (int mi = 0; mi < 8; ++mi) {
      const int mbase = m0 + wm*128 + (mi >> 2)*64 + (mi & 3)*16 + lq*4;
#pragma unroll
      for (int nj = 0; nj < 4; ++nj) {
        const int n = n0 + wn*64 + (nj >> 1)*32 + (nj & 1)*16 + l15;
        const float bn_ = bq[n];
#pragma unroll
        for (int r = 0; r < 4; ++r)
          Cq[(long)(mbase + r) * 512 + n] = f2bf(acc[mi][nj][r] + bn_);
      }
    }
  } else {
    // KV (2D,S): bias bkv[m], maxpool over n(time)-pairs.
    ushort_t* Ckv = KV + (long)z * 1024 * 1024;
#pragma unroll
    for (int mi = 0; mi < 8; ++mi) {
      const int mbase = m0 + wm*128 + (mi >> 2)*64 + (mi & 3)*16 + lq*4;
#pragma unroll
      for (int nj = 0; nj < 4; ++nj) {
        const int n = n0 + wn*64 + (nj >> 1)*32 + (nj & 1)*16 + l15;
#pragma unroll
        for (int r = 0; r < 4; ++r) {
          float v = acc[mi][nj][r] + bkv[mbase + r];
          float o = __shfl_xor(v, 1);
          float w = fmaxf(v, o);
          if ((lane & 1) == 0)
            Ckv[(long)(mbase + r) * 1024 + (n >> 1)] = f2bf(w);
        }
      }
    }
  }
}

// ============================================================================
// 128x128 GEMM (m97 structure) for small grids.
// ============================================================================
template<int BIASM, int POOLM, bool OUTF32>
__global__ __launch_bounds__(256)
void gemm_bt(const ushort_t* __restrict__ A, long aStr,
             const ushort_t* __restrict__ B, long bStr,
             void* __restrict__ Cp, long cStr,
             int K, int lda, int ldb, int ldc,
             const float* __restrict__ bias, float scale)
{
  __shared__ ushort_t As[BM][BKK];
  __shared__ ushort_t Bs[BN][BKK];
  A += (long)blockIdx.z * aStr;
  B += (long)blockIdx.z * bStr;
  float* Cf = (float*)Cp + (OUTF32 ? (long)blockIdx.z * cStr : 0);
  ushort_t* Cb = (ushort_t*)Cp + (OUTF32 ? 0 : (long)blockIdx.z * cStr);
  const int m0 = blockIdx.y * BM;
  const int n0 = blockIdx.x * BN;
  const int tid = threadIdx.x;
  const int lane = tid & 63;
  const int wm = (tid >> 7) & 1;
  const int wn = (tid >> 6) & 1;
  const int ar = tid >> 3;
  const int ac = (tid & 7) * 8;

  floatx4 acc[4][4];
#pragma unroll
  for (int i = 0; i < 4; ++i)
#pragma unroll
    for (int j = 0; j < 4; ++j)
#pragma unroll
      for (int r = 0; r < 4; ++r) acc[i][j][r] = 0.0f;

  const int q8 = (lane >> 4) * 8;
  const int l15 = lane & 15;

  const ushort_t* gA = &A[(long)(m0 + ar) * lda + ac];
  const ushort_t* gB = &B[(long)(n0 + ar) * ldb + ac];
  const long aRow32 = (long)32 * lda;
  const long bRow32 = (long)32 * ldb;

  for (int k0 = 0; k0 < K; k0 += BKK) {
#pragma unroll
    for (int p = 0; p < 4; ++p)
      async16(gA + p * aRow32 + k0, &As[p * 32 + ar][ac]);
#pragma unroll
    for (int p = 0; p < 4; ++p)
      async16(gB + p * bRow32 + k0, &Bs[p * 32 + ar][ac]);
    __syncthreads();
#pragma unroll
    for (int kk = 0; kk < 2; ++kk) {
      const int kr = kk * 32 + q8;
      bf16x8 af[4], bfr[4];
#pragma unroll
      for (int i = 0; i < 4; ++i) {
        af[i]  = *(const bf16x8*)(&As[wm * 64 + i * 16 + l15][kr]);
        bfr[i] = *(const bf16x8*)(&Bs[wn * 64 + i * 16 + l15][kr]);
      }
#pragma unroll
      for (int i = 0; i < 4; ++i)
#pragma unroll
        for (int j = 0; j < 4; ++j)
          acc[i][j] = __builtin_amdgcn_mfma_f32_16x16x32_bf16(af[i], bfr[j], acc[i][j], 0, 0, 0);
    }
    __syncthreads();
  }

#pragma unroll
  for (int i = 0; i < 4; ++i) {
    const int mbase = m0 + wm * 64 + i * 16 + (lane >> 4) * 4;
#pragma unroll
    for (int j = 0; j < 4; ++j) {
      const int n = n0 + wn * 64 + j * 16 + l15;
      float v[4];
#pragma unroll
      for (int r = 0; r < 4; ++r) {
        v[r] = acc[i][j][r] * scale;
        if (BIASM == 1) v[r] += bias[mbase + r];
      }
      if (BIASM == 2) {
        const float bn_ = bias[n];
#pragma unroll
        for (int r = 0; r < 4; ++r) v[r] += bn_;
      }
      if (POOLM == 0) {
#pragma unroll
        for (int r = 0; r < 4; ++r) {
          if (OUTF32) Cf[(long)(mbase + r) * ldc + n] = v[r];
          else        Cb[(long)(mbase + r) * ldc + n] = f2bf(v[r]);
        }
      } else if (POOLM == 1) {
#pragma unroll
        for (int r = 0; r < 4; ++r) {
          float o = __shfl_xor(v[r], 1);
          float w = fmaxf(v[r], o);
          if ((lane & 1) == 0) {
            if (OUTF32) Cf[(long)(mbase + r) * ldc + (n >> 1)] = w;
            else        Cb[(long)(mbase + r) * ldc + (n >> 1)] = f2bf(w);
          }
        }
      } else {
        float w0 = fmaxf(v[0], v[1]);
        float w1 = fmaxf(v[2], v[3]);
        const int mh = mbase >> 1;
        if (OUTF32) {
          Cf[(long)mh * ldc + n] = w0;
          Cf[(long)(mh + 1) * ldc + n] = w1;
        } else {
          Cb[(long)mh * ldc + n] = f2bf(w0);
          Cb[(long)(mh + 1) * ldc + n] = f2bf(w1);
        }
      }
    }
  }
}

// dst[t][c] = bf16(src[c][t]) per batch z. 64x64 tiles; float4 reads,
// ushort8 writes.
__global__ __launch_bounds__(256)
void transpose_f32_bf16(const float* __restrict__ src, ushort_t* __restrict__ dst,
                        int Rr, int Cl)
{
  __shared__ ushort_t tileT[64][72];
  const long boff = (long)blockIdx.z * Rr * Cl;
  const int t0 = blockIdx.x * 64;
  const int r0 = blockIdx.y * 64;
  const int tx = threadIdx.x & 15;
  const int ty = threadIdx.x >> 4;
#pragma unroll
  for (int i = 0; i < 4; ++i) {
    const int c = ty + 16 * i;
    floatx4 v = *(const floatx4*)&src[boff + (long)(r0 + c) * Cl + t0 + 4 * tx];
#pragma unroll
    for (int j = 0; j < 4; ++j) tileT[4 * tx + j][c] = f2bf(v[j]);
  }
  __syncthreads();
  const int cx = threadIdx.x & 7;
  const int tw = threadIdx.x >> 3;
#pragma unroll
  for (int i = 0; i < 2; ++i) {
    const int t = tw + 32 * i;
    ushortx8 w = *(const ushortx8*)&tileT[t][8 * cx];
    *(ushortx8*)&dst[boff + (long)(t0 + t) * Rr + r0 + 8 * cx] = w;
  }
}

// Weights fp32 -> bf16 (contiguous) + concat bias bkv[1024] = {bk, bv}.
__global__ __launch_bounds__(256)
void convert4(const float* __restrict__ a, const float* __restrict__ b,
              const float* __restrict__ c, const float* __restrict__ d,
              ushort_t* __restrict__ dst, int n,
              const float* __restrict__ bk, const float* __restrict__ bv,
              float* __restrict__ bkv)
{
  const float* srcs[4] = {a, b, c, d};
  const float* s = srcs[blockIdx.y];
  int i = blockIdx.x * 256 + threadIdx.x;
  if (i < n) dst[(long)blockIdx.y * n + i] = f2bf(s[i]);
  if (blockIdx.y == 0 && blockIdx.x == 0) {
    for (int j = threadIdx.x; j < 1024; j += 256)
      bkv[j] = (j < 512) ? bk[j] : bv[j - 512];
  }
}

// out = gamma*(yb-mean)*rstd + beta + x ; yb is bf16 pre-BN y. One block per
// (b,c) row; per-block reduce of 128 L2-hot pstat partials, then apply.
__global__ __launch_bounds__(256)
void bn_apply(const ushort_t* __restrict__ yb, const float* __restrict__ x,
              float* __restrict__ out, const float2* __restrict__ pstat,
              const float* __restrict__ gamma, const float* __restrict__ beta)
{
  const int bc = blockIdx.x;
  const int c = bc & 1023;
  float s = 0.0f, s2 = 0.0f;
  if (threadIdx.x < 128) {
    float2 p = pstat[(long)threadIdx.x * 1024 + c];
    s = p.x; s2 = p.y;
  }
#pragma unroll
  for (int o = 32; o > 0; o >>= 1) { s += __shfl_down(s, o); s2 += __shfl_down(s2, o); }
  __shared__ float red[4];
  __shared__ float smv[2];
  const int w = threadIdx.x >> 6;
  if ((threadIdx.x & 63) == 0 && w < 2) { red[w] = s; red[2 + w] = s2; }
  __syncthreads();
  if (threadIdx.x == 0) {
    float ts = red[0] + red[1], ts2 = red[2] + red[3];
    const float inv = 1.0f / (16.0f * 2048.0f);
    float mean = ts * inv;
    float var = ts2 * inv - mean * mean;
    smv[0] = mean;
    smv[1] = rsqrtf(var + 1e-5f);
  }
  __syncthreads();
  const float mean = smv[0];
  const float g = gamma[c] * smv[1];
  const float bt = beta[c];
  const long off = (long)bc * 2048;
  const ushortx8* yp = (const ushortx8*)(yb + off);
  const floatx4* xp = (const floatx4*)(x + off);
  floatx4* op = (floatx4*)(out + off);
  const int t = threadIdx.x;           // 256 threads x 8 elems = 2048
  ushortx8 v8 = yp[t];
  floatx4 x0 = xp[2 * t], x1 = xp[2 * t + 1];
  floatx4 o0, o1;
#pragma unroll
  for (int r = 0; r < 4; ++r) o0[r] = (bf2f(v8[r]) - mean) * g + bt + x0[r];
#pragma unroll
  for (int r = 0; r < 4; ++r) o1[r] = (bf2f(v8[4 + r]) - mean) * g + bt + x1[r];
  op[2 * t] = o0;
  op[2 * t + 1] = o1;
}

extern "C" void kernel_launch(void* const* d_in, const int* in_sizes, int n_in,
                              void* d_out, int out_size, void* d_ws, size_t ws_size,
                              hipStream_t stream) {
  (void)in_sizes; (void)n_in; (void)out_size; (void)ws_size;
  const float* x  = (const float*)d_in[0];
  const float* Wq = (const float*)d_in[1];
  const float* bq = (const float*)d_in[2];
  const float* Wk = (const float*)d_in[3];
  const float* bk = (const float*)d_in[4];
  const float* Wv = (const float*)d_in[5];
  const float* bv = (const float*)d_in[6];
  const float* Wo = (const float*)d_in[7];
  const float* bo = (const float*)d_in[8];
  const float* gamma = (const float*)d_in[9];
  const float* beta  = (const float*)d_in[10];
  float* out = (float*)d_out;

  const int Cc = 1024, T = 2048, D = 512, S = 1024;

  // Chain: QKV proj (fused) -> WtT = Kd V^T -> Wco = Wo WtT^T/T ->
  // yb = bf16(Wco Qt^T + bo) with fused BN partials -> bn_apply.
  ushort_t* ws   = (ushort_t*)d_ws;
  ushort_t* xT   = ws;                  // (B,T,C)  33,554,432
  ushort_t* Qt   = ws + 33554432;       // (B,T,D)  16,777,216
  ushort_t* KV   = ws + 50331648;       // (B,2D,S) 16,777,216
  ushort_t* WtT  = ws + 67108864;       // (B,D,D)   4,194,304
  ushort_t* Wco  = ws + 71303168;       // (B,C,D)   8,388,608
  ushort_t* yb   = ws + 79691776;       // (B,C,T)  33,554,432 bf16 pre-BN y
  ushort_t* Wq_b = ws + 113246208;      //  2,097,152 (Wq,Wk,Wv,Wo contiguous)
  ushort_t* Wo_b = ws + 113246208 + 3 * 524288;
  float*    bkv  = (float*)(ws + 115343360);    // 1024 floats
  float2*   pstat = (float2*)(ws + 115345408);  // 128*1024 float2 = 1 MB

  dim3 blk(256);
  dim3 blk512(512);

  // 0. Weights fp32 -> bf16 + concat bias [bk;bv].
  convert4<<<dim3(2048, 4), blk, 0, stream>>>(Wq, Wk, Wv, Wo, Wq_b, D * Cc,
                                              bk, bv, bkv);

  // 1. xT = bf16(x^T).
  transpose_f32_bf16<<<dim3(T / 32 / 2, Cc / 64, 16), blk, 0, stream>>>(x, xT, Cc, T);

  // 2. Fused Q + KV projection (768 blocks = 3 clean rounds).
  gemm_qkv<<<dim3(48, 1, 16), blk512, 0, stream>>>(xT, Wq_b, Qt, KV, bq, bkv);

  // 3. WtT (D,D) = Kd x V^T : K=S.
  gemm_bt<0, 0, false><<<dim3(D / 128, D / 128, 16), blk, 0, stream>>>(
      KV, (long)2 * D * S, KV + (long)D * S, (long)2 * D * S, WtT, (long)D * D,
      S, S, S, D, nullptr, 1.0f);
  // 4. Wco (C,D) = Wo x WtT^T / T : K=D.
  gemm_bt<0, 0, false><<<dim3(D / 128, Cc / 128, 16), blk, 0, stream>>>(
      Wo_b, 0, WtT, (long)D * D, Wco, (long)Cc * D,
      D, D, D, D, nullptr, 1.0f / 2048.0f);

  // 5. yb = bf16(Wco x Qt^T + bo), (B,C,T); fused BN partials.
  gemm256<1, 0, false, true><<<dim3(T / 256, Cc / 256, 16), blk512, 0, stream>>>(
      Wco, (long)Cc * D, Qt, (long)T * D, yb, (long)Cc * T,
      D, D, D, T, bo, 1.0f, pstat);

  // 6. BN finalize (folded) + apply + residual -> fp32 out.
  bn_apply<<<dim3(16384), blk, 0, stream>>>(yb, x, out, pstat, gamma, beta);
}